// Round 1
// baseline (1082.214 us; speedup 1.0000x reference)
//
#include <hip/hip_runtime.h>
#include <hip/hip_bf16.h>
#include <math.h>

#define HD 4
#define CH 64
#define GHC 256
#define NEG 0.2f

__device__ __forceinline__ float wred_sum(float v){
  #pragma unroll
  for (int o = 32; o > 0; o >>= 1) v += __shfl_down(v, o);
  return v;
}

// ---------------- CSR build ----------------
__global__ __launch_bounds__(256)
void count_deg(const int* __restrict__ ei, int E, int N, int* __restrict__ cnt){
  int i = blockIdx.x * 256 + threadIdx.x;
  int tot = E + N;
  if (i >= tot) return;
  int dst = (i < E) ? ei[E + i] : (i - E);
  atomicAdd(&cnt[dst], 1);
}

__global__ __launch_bounds__(256)
void scan_local(const int* __restrict__ cnt, int N, int* __restrict__ off, int* __restrict__ blkS){
  __shared__ int sh[256];
  int tid = threadIdx.x;
  int i = blockIdx.x * 256 + tid;
  int v = (i < N) ? cnt[i] : 0;
  sh[tid] = v;
  __syncthreads();
  for (int o = 1; o < 256; o <<= 1){
    int t = (tid >= o) ? sh[tid - o] : 0;
    __syncthreads();
    sh[tid] += t;
    __syncthreads();
  }
  if (i < N) off[i] = sh[tid] - v;      // exclusive within block
  if (tid == 255) blkS[blockIdx.x] = sh[255];
}

__global__ __launch_bounds__(256)
void scan_carry(const int* __restrict__ blkS, int nb, int* __restrict__ carry){
  __shared__ int sh[256];
  int tid = threadIdx.x;
  int v = (tid < nb) ? blkS[tid] : 0;   // requires nb <= 256 (N <= 65536; N=50000 -> nb=196)
  sh[tid] = v;
  __syncthreads();
  for (int o = 1; o < 256; o <<= 1){
    int t = (tid >= o) ? sh[tid - o] : 0;
    __syncthreads();
    sh[tid] += t;
    __syncthreads();
  }
  if (tid < nb) carry[tid] = sh[tid] - v;
}

__global__ __launch_bounds__(256)
void scan_add(int* __restrict__ off, const int* __restrict__ carry, int N, int Etot){
  int i = blockIdx.x * 256 + threadIdx.x;
  if (i < N) off[i] += carry[blockIdx.x];
  if (i == 0) off[N] = Etot;
}

__global__ __launch_bounds__(256)
void fill_csr(const int* __restrict__ ei, int E, int N, const int* __restrict__ off,
              int* __restrict__ fill, int* __restrict__ csr){
  int i = blockIdx.x * 256 + threadIdx.x;
  int tot = E + N;
  if (i >= tot) return;
  int src, dst;
  if (i < E){ src = ei[i]; dst = ei[E + i]; }
  else { src = dst = i - E; }
  int pos = off[dst] + atomicAdd(&fill[dst], 1);
  csr[pos] = src;
}

// ---------------- per-layer kernels ----------------
// h = x @ W ([N,FIN]@[FIN,256]); fused attention logits s,d ([N,4]).
template<int FIN>
__global__ __launch_bounds__(256)
void feat_gemm(const float* __restrict__ x, const float* __restrict__ W,
               const float* __restrict__ a_s, const float* __restrict__ a_d,
               float* __restrict__ h, float* __restrict__ s_log, float* __restrict__ d_log,
               int N)
{
  const int tid = threadIdx.x;
  const int n0 = blockIdx.x * 16;
  __shared__ float xs[16][FIN];
  for (int idx = tid; idx < 16 * FIN; idx += 256){
    int nn = idx / FIN, k = idx % FIN;
    int node = n0 + nn;
    xs[nn][k] = (node < N) ? x[(size_t)node * FIN + k] : 0.f;
  }
  __syncthreads();
  float acc[16];
  #pragma unroll
  for (int i = 0; i < 16; i++) acc[i] = 0.f;
  #pragma unroll 4
  for (int k = 0; k < FIN; k++){
    float wv = W[k * GHC + tid];
    #pragma unroll
    for (int nn = 0; nn < 16; nn++) acc[nn] += xs[nn][k] * wv;
  }
  const float as = a_s[tid], ad = a_d[tid];
  const int hd = tid >> 6, ln = tid & 63;
  #pragma unroll
  for (int nn = 0; nn < 16; nn++){
    int node = n0 + nn;
    if (node < N){
      h[(size_t)node * GHC + tid] = acc[nn];
      float vs = wred_sum(acc[nn] * as);
      float vd = wred_sum(acc[nn] * ad);
      if (ln == 0){ s_log[node * HD + hd] = vs; d_log[node * HD + hd] = vd; }
    }
  }
}

// One block (256 thr) per destination node: segment softmax + weighted gather-sum.
__global__ __launch_bounds__(256)
void gat_aggregate(const float* __restrict__ h, const float* __restrict__ s_log,
                   const float* __restrict__ d_log, const int* __restrict__ off,
                   const int* __restrict__ csr, const float* __restrict__ bias,
                   float* __restrict__ out, int N)
{
  const int n = blockIdx.x;
  if (n >= N) return;
  const int tid = threadIdx.x;
  const int hd = tid >> 6, ln = tid & 63;
  const int beg = off[n];
  const int deg = off[n + 1] - beg;

  __shared__ float d4[HD];
  __shared__ float red[4][HD];
  __shared__ float bcast[HD];
  __shared__ int   srcl[256];
  __shared__ float exv[256 * 5];   // stride 5: bank-conflict-free writes

  if (tid < HD) d4[tid] = d_log[n * HD + tid];
  __syncthreads();

  // pass 1: segment max per head
  float m[HD];
  #pragma unroll
  for (int i = 0; i < HD; i++) m[i] = -INFINITY;
  for (int base = 0; base < deg; base += 256){
    int k = base + tid;
    float lr[HD];
    if (k < deg){
      int s = csr[beg + k];
      #pragma unroll
      for (int i = 0; i < HD; i++){
        float v = s_log[s * HD + i] + d4[i];
        lr[i] = (v >= 0.f) ? v : NEG * v;
      }
    } else {
      #pragma unroll
      for (int i = 0; i < HD; i++) lr[i] = -INFINITY;
    }
    #pragma unroll
    for (int i = 0; i < HD; i++){
      float v = lr[i];
      #pragma unroll
      for (int o = 32; o > 0; o >>= 1) v = fmaxf(v, __shfl_down(v, o));
      if (ln == 0) red[tid >> 6][i] = v;
    }
    __syncthreads();
    if (tid == 0){
      #pragma unroll
      for (int i = 0; i < HD; i++)
        bcast[i] = fmaxf(fmaxf(red[0][i], red[1][i]), fmaxf(red[2][i], red[3][i]));
    }
    __syncthreads();
    #pragma unroll
    for (int i = 0; i < HD; i++) m[i] = fmaxf(m[i], bcast[i]);
  }

  // pass 2: exp, denom, and unnormalized accumulation (divide at end)
  float den[HD];
  #pragma unroll
  for (int i = 0; i < HD; i++) den[i] = 0.f;
  float acc = 0.f;
  for (int base = 0; base < deg; base += 256){
    int k = base + tid;
    float ex[HD];
    int s = 0;
    if (k < deg){
      s = csr[beg + k];
      #pragma unroll
      for (int i = 0; i < HD; i++){
        float v = s_log[s * HD + i] + d4[i];
        v = (v >= 0.f) ? v : NEG * v;
        ex[i] = expf(v - m[i]);
      }
    } else {
      #pragma unroll
      for (int i = 0; i < HD; i++) ex[i] = 0.f;
    }
    srcl[tid] = s;
    #pragma unroll
    for (int i = 0; i < HD; i++) exv[tid * 5 + i] = ex[i];
    #pragma unroll
    for (int i = 0; i < HD; i++){
      float v = wred_sum(ex[i]);
      if (ln == 0) red[tid >> 6][i] = v;
    }
    __syncthreads();
    if (tid == 0){
      #pragma unroll
      for (int i = 0; i < HD; i++)
        bcast[i] = red[0][i] + red[1][i] + red[2][i] + red[3][i];
    }
    __syncthreads();
    #pragma unroll
    for (int i = 0; i < HD; i++) den[i] += bcast[i];
    int cnt = min(256, deg - base);
    for (int e = 0; e < cnt; e++){
      acc += exv[e * 5 + hd] * h[(size_t)srcl[e] * GHC + tid];
    }
    __syncthreads();
  }
  float dn = fmaxf(den[hd], 1e-16f);
  out[(size_t)n * GHC + tid] = acc / dn + bias[tid];
}

// out[n,c] = (relu?)(in[n,:]@w[:,c] + b[c]); in [N,256], w [256,64]
template<bool RELU>
__global__ __launch_bounds__(256)
void head_linear(const float* __restrict__ in, const float* __restrict__ w,
                 const float* __restrict__ b, float* __restrict__ out, int N)
{
  const int tid = threadIdx.x;
  const int n0 = blockIdx.x * 16;
  __shared__ float xs[16][GHC];  // 16 KB
  for (int idx = tid; idx < 16 * GHC; idx += 256){
    int nn = idx >> 8, j = idx & 255;
    int node = n0 + nn;
    xs[nn][j] = (node < N) ? in[(size_t)node * GHC + j] : 0.f;
  }
  __syncthreads();
  const int c = tid & 63, q = tid >> 6;
  float acc[4] = {0.f, 0.f, 0.f, 0.f};
  for (int j = 0; j < GHC; j++){
    float wv = w[j * CH + c];
    #pragma unroll
    for (int i = 0; i < 4; i++) acc[i] += xs[q * 4 + i][j] * wv;
  }
  const float bb = b[c];
  #pragma unroll
  for (int i = 0; i < 4; i++){
    int node = n0 + q * 4 + i;
    if (node < N){
      float v = acc[i] + bb;
      if (RELU) v = fmaxf(v, 0.f);
      out[(size_t)node * CH + c] = v;
    }
  }
}

// ---------------- pooling + MLP head ----------------
__global__ __launch_bounds__(256)
void pool_kernel(const float* __restrict__ x3, const int* __restrict__ batch,
                 float* __restrict__ pS, int* __restrict__ pC, int N)
{
  int idx = blockIdx.x * 256 + threadIdx.x;
  int n = idx >> 6, c = idx & 63;
  if (n >= N) return;
  int g = batch[n];
  atomicAdd(&pS[g * CH + c], x3[(size_t)n * CH + c]);
  if (c == 0) atomicAdd(&pC[g], 1);
}

__global__ __launch_bounds__(256)
void mlp1_kernel(const float* __restrict__ pS, const int* __restrict__ pC,
                 const float* __restrict__ w, const float* __restrict__ b,
                 float* __restrict__ g1)
{
  int g = blockIdx.x;
  int tid = threadIdx.x;
  __shared__ float mean[CH];
  if (tid < CH){
    float cf = (float)max(pC[g], 1);
    mean[tid] = pS[g * CH + tid] / cf;
  }
  __syncthreads();
  float acc = b[tid];
  for (int c = 0; c < CH; c++) acc += mean[c] * w[c * 256 + tid];
  g1[g * 256 + tid] = fmaxf(acc, 0.f);
}

__global__ __launch_bounds__(256)
void mlp2_kernel(const float* __restrict__ g1, const float* __restrict__ w,
                 const float* __restrict__ b, float* __restrict__ out)
{
  int g = blockIdx.x;
  int tid = threadIdx.x;
  __shared__ float row[256];
  row[tid] = g1[g * 256 + tid];
  __syncthreads();
  float acc = b[tid];
  for (int k = 0; k < 256; k++) acc += row[k] * w[k * 256 + tid];
  out[g * 256 + tid] = acc;
}

// ---------------- launcher ----------------
extern "C" void kernel_launch(void* const* d_in, const int* in_sizes, int n_in,
                              void* d_out, int out_size, void* d_ws, size_t ws_size,
                              hipStream_t stream)
{
  const float* x     = (const float*)d_in[0];
  const int*   ei    = (const int*)d_in[1];
  const int*   batch = (const int*)d_in[2];
  const float* W1  = (const float*)d_in[4];
  const float* a1s = (const float*)d_in[5];
  const float* a1d = (const float*)d_in[6];
  const float* b1  = (const float*)d_in[7];
  const float* h1w = (const float*)d_in[8];
  const float* h1b = (const float*)d_in[9];
  const float* W2  = (const float*)d_in[10];
  const float* a2s = (const float*)d_in[11];
  const float* a2d = (const float*)d_in[12];
  const float* b2  = (const float*)d_in[13];
  const float* h2w = (const float*)d_in[14];
  const float* h2b = (const float*)d_in[15];
  const float* W3  = (const float*)d_in[16];
  const float* a3s = (const float*)d_in[17];
  const float* a3d = (const float*)d_in[18];
  const float* b3  = (const float*)d_in[19];
  const float* h3w = (const float*)d_in[20];
  const float* h3b = (const float*)d_in[21];
  const float* m1w = (const float*)d_in[22];
  const float* m1b = (const float*)d_in[23];
  const float* m2w = (const float*)d_in[24];
  const float* m2b = (const float*)d_in[25];

  const int N = in_sizes[0] / 32;
  const int E = in_sizes[1] / 2;
  const int G = out_size / 256;
  const int Etot = E + N;
  const int nb = (N + 255) / 256;

  char* p = (char*)d_ws;
  auto alloc = [&](size_t bytes) -> void* {
    void* r = (void*)p;
    p += ((bytes + 255) / 256) * 256;
    return r;
  };
  float* buf_h   = (float*)alloc((size_t)N * GHC * 4);
  float* buf_agg = (float*)alloc((size_t)N * GHC * 4);
  float* buf_x   = (float*)alloc((size_t)N * CH * 4);
  float* s_log   = (float*)alloc((size_t)N * HD * 4);
  float* d_log   = (float*)alloc((size_t)N * HD * 4);
  int*   counts  = (int*)alloc((size_t)N * 4);
  int*   offs    = (int*)alloc((size_t)(N + 1) * 4);
  int*   fill    = (int*)alloc((size_t)N * 4);
  int*   csr     = (int*)alloc((size_t)Etot * 4);
  int*   blkS    = (int*)alloc((size_t)nb * 4);
  int*   carry   = (int*)alloc((size_t)nb * 4);
  float* poolS   = (float*)alloc((size_t)G * CH * 4);
  int*   poolC   = (int*)alloc((size_t)G * 4);
  float* g1buf   = (float*)alloc((size_t)G * 256 * 4);

  hipMemsetAsync(counts, 0, (size_t)N * 4, stream);
  hipMemsetAsync(fill,   0, (size_t)N * 4, stream);
  hipMemsetAsync(poolS,  0, (size_t)G * CH * 4, stream);
  hipMemsetAsync(poolC,  0, (size_t)G * 4, stream);

  count_deg<<<(Etot + 255) / 256, 256, 0, stream>>>(ei, E, N, counts);
  scan_local<<<nb, 256, 0, stream>>>(counts, N, offs, blkS);
  scan_carry<<<1, 256, 0, stream>>>(blkS, nb, carry);
  scan_add<<<nb, 256, 0, stream>>>(offs, carry, N, Etot);
  fill_csr<<<(Etot + 255) / 256, 256, 0, stream>>>(ei, E, N, offs, fill, csr);

  const int gb = (N + 15) / 16;

  feat_gemm<32><<<gb, 256, 0, stream>>>(x, W1, a1s, a1d, buf_h, s_log, d_log, N);
  gat_aggregate<<<N, 256, 0, stream>>>(buf_h, s_log, d_log, offs, csr, b1, buf_agg, N);
  head_linear<true><<<gb, 256, 0, stream>>>(buf_agg, h1w, h1b, buf_x, N);

  feat_gemm<64><<<gb, 256, 0, stream>>>(buf_x, W2, a2s, a2d, buf_h, s_log, d_log, N);
  gat_aggregate<<<N, 256, 0, stream>>>(buf_h, s_log, d_log, offs, csr, b2, buf_agg, N);
  head_linear<true><<<gb, 256, 0, stream>>>(buf_agg, h2w, h2b, buf_x, N);

  feat_gemm<64><<<gb, 256, 0, stream>>>(buf_x, W3, a3s, a3d, buf_h, s_log, d_log, N);
  gat_aggregate<<<N, 256, 0, stream>>>(buf_h, s_log, d_log, offs, csr, b3, buf_agg, N);
  head_linear<false><<<gb, 256, 0, stream>>>(buf_agg, h3w, h3b, buf_x, N);

  pool_kernel<<<((size_t)N * CH + 255) / 256, 256, 0, stream>>>(buf_x, batch, poolS, poolC, N);
  mlp1_kernel<<<G, 256, 0, stream>>>(poolS, poolC, m1w, m1b, g1buf);
  mlp2_kernel<<<G, 256, 0, stream>>>(g1buf, m2w, m2b, (float*)d_out);
}

// Round 2
// 745.626 us; speedup vs baseline: 1.4514x; 1.4514x over previous
//
#include <hip/hip_runtime.h>
#include <hip/hip_bf16.h>
#include <hip/hip_fp16.h>
#include <math.h>

#define HD 4
#define CH 64
#define GHC 256
#define NEG 0.2f

#define WAVE_SYNC() do { __builtin_amdgcn_wave_barrier(); \
                         asm volatile("s_waitcnt lgkmcnt(0)" ::: "memory"); } while (0)

__device__ __forceinline__ float wred_sum_down(float v){
  #pragma unroll
  for (int o = 32; o > 0; o >>= 1) v += __shfl_down(v, o);
  return v;
}
__device__ __forceinline__ float wred_sum64(float v){
  #pragma unroll
  for (int o = 32; o > 0; o >>= 1) v += __shfl_xor(v, o);
  return v;
}
__device__ __forceinline__ float wred_max64(float v){
  #pragma unroll
  for (int o = 32; o > 0; o >>= 1) v = fmaxf(v, __shfl_xor(v, o));
  return v;
}

// ---------------- CSR build ----------------
__global__ __launch_bounds__(256)
void count_deg(const int* __restrict__ ei, int E, int N, int* __restrict__ cnt){
  int i = blockIdx.x * 256 + threadIdx.x;
  int tot = E + N;
  if (i >= tot) return;
  int dst = (i < E) ? ei[E + i] : (i - E);
  atomicAdd(&cnt[dst], 1);
}

__global__ __launch_bounds__(256)
void scan_local(const int* __restrict__ cnt, int N, int* __restrict__ off, int* __restrict__ blkS){
  __shared__ int sh[256];
  int tid = threadIdx.x;
  int i = blockIdx.x * 256 + tid;
  int v = (i < N) ? cnt[i] : 0;
  sh[tid] = v;
  __syncthreads();
  for (int o = 1; o < 256; o <<= 1){
    int t = (tid >= o) ? sh[tid - o] : 0;
    __syncthreads();
    sh[tid] += t;
    __syncthreads();
  }
  if (i < N) off[i] = sh[tid] - v;      // exclusive within block
  if (tid == 255) blkS[blockIdx.x] = sh[255];
}

__global__ __launch_bounds__(256)
void scan_carry(const int* __restrict__ blkS, int nb, int* __restrict__ carry){
  __shared__ int sh[256];
  int tid = threadIdx.x;
  int v = (tid < nb) ? blkS[tid] : 0;   // requires nb <= 256 (N=50000 -> nb=196)
  sh[tid] = v;
  __syncthreads();
  for (int o = 1; o < 256; o <<= 1){
    int t = (tid >= o) ? sh[tid - o] : 0;
    __syncthreads();
    sh[tid] += t;
    __syncthreads();
  }
  if (tid < nb) carry[tid] = sh[tid] - v;
}

__global__ __launch_bounds__(256)
void scan_add(int* __restrict__ off, const int* __restrict__ carry, int N, int Etot){
  int i = blockIdx.x * 256 + threadIdx.x;
  if (i < N) off[i] += carry[blockIdx.x];
  if (i == 0) off[N] = Etot;
}

__global__ __launch_bounds__(256)
void fill_csr(const int* __restrict__ ei, int E, int N, const int* __restrict__ off,
              int* __restrict__ fill, int* __restrict__ csr){
  int i = blockIdx.x * 256 + threadIdx.x;
  int tot = E + N;
  if (i >= tot) return;
  int src, dst;
  if (i < E){ src = ei[i]; dst = ei[E + i]; }
  else { src = dst = i - E; }
  int pos = off[dst] + atomicAdd(&fill[dst], 1);
  csr[pos] = src;
}

// ---------------- per-layer kernels ----------------
// h = x @ W ([N,FIN]@[FIN,256]) -> fp16; fused attention logits s,d ([N,4]).
template<int FIN>
__global__ __launch_bounds__(256)
void feat_gemm(const float* __restrict__ x, const float* __restrict__ W,
               const float* __restrict__ a_s, const float* __restrict__ a_d,
               __half* __restrict__ h, float* __restrict__ s_log, float* __restrict__ d_log,
               int N)
{
  const int tid = threadIdx.x;
  const int n0 = blockIdx.x * 16;
  __shared__ float xs[16][FIN];
  for (int idx = tid; idx < 16 * FIN; idx += 256){
    int nn = idx / FIN, k = idx % FIN;
    int node = n0 + nn;
    xs[nn][k] = (node < N) ? x[(size_t)node * FIN + k] : 0.f;
  }
  __syncthreads();
  float acc[16];
  #pragma unroll
  for (int i = 0; i < 16; i++) acc[i] = 0.f;
  #pragma unroll 4
  for (int k = 0; k < FIN; k++){
    float wv = W[k * GHC + tid];
    #pragma unroll
    for (int nn = 0; nn < 16; nn++) acc[nn] += xs[nn][k] * wv;
  }
  const float as = a_s[tid], ad = a_d[tid];
  const int hd = tid >> 6, ln = tid & 63;
  #pragma unroll
  for (int nn = 0; nn < 16; nn++){
    int node = n0 + nn;
    if (node < N){
      h[(size_t)node * GHC + tid] = __float2half(acc[nn]);
      float vs = wred_sum_down(acc[nn] * as);
      float vd = wred_sum_down(acc[nn] * ad);
      if (ln == 0){ s_log[node * HD + hd] = vs; d_log[node * HD + hd] = vd; }
    }
  }
}

// One WAVE per destination node: segment softmax + weighted gather-sum.
// lane owns channels [4*lane .. 4*lane+3]; head = lane>>4.
__global__ __launch_bounds__(256)
void gat_aggregate(const __half* __restrict__ h16, const float* __restrict__ s_log,
                   const float* __restrict__ d_log, const int* __restrict__ off,
                   const int* __restrict__ csr, const float* __restrict__ bias,
                   float* __restrict__ out, int N)
{
  __shared__ float sq[4][64 * 5];   // per-wave: 64 edges x {alpha0..3, src}
  const int wv   = threadIdx.x >> 6;
  const int lane = threadIdx.x & 63;
  const int n = blockIdx.x * 4 + wv;
  if (n >= N) return;
  const int head = lane >> 4;
  const int beg = off[n];
  const int deg = off[n + 1] - beg;

  const float4 d4v = reinterpret_cast<const float4*>(d_log)[n];
  const float d4[4] = {d4v.x, d4v.y, d4v.z, d4v.w};

  float m[4], den[4], ex[4];
  int s = 0;

  // ---- chunk 0 softmax stats (always) ----
  {
    const int k = lane;
    const bool act = k < deg;
    float v[4];
    if (act){
      s = csr[beg + k];
      float4 sl = reinterpret_cast<const float4*>(s_log)[s];
      float t[4] = {sl.x, sl.y, sl.z, sl.w};
      #pragma unroll
      for (int i = 0; i < 4; i++){ float u = t[i] + d4[i]; v[i] = (u >= 0.f) ? u : NEG * u; }
    } else {
      #pragma unroll
      for (int i = 0; i < 4; i++) v[i] = -INFINITY;
    }
    #pragma unroll
    for (int i = 0; i < 4; i++){
      m[i] = wred_max64(v[i]);
      ex[i] = act ? __expf(v[i] - m[i]) : 0.f;
      den[i] = wred_sum64(ex[i]);
    }
  }
  // ---- remaining chunks (rare: deg > 64), online rescale ----
  for (int base = 64; base < deg; base += 64){
    const int k = base + lane;
    const bool act = k < deg;
    float v[4]; int s2 = 0;
    if (act){
      s2 = csr[beg + k];
      float4 sl = reinterpret_cast<const float4*>(s_log)[s2];
      float t[4] = {sl.x, sl.y, sl.z, sl.w};
      #pragma unroll
      for (int i = 0; i < 4; i++){ float u = t[i] + d4[i]; v[i] = (u >= 0.f) ? u : NEG * u; }
    } else {
      #pragma unroll
      for (int i = 0; i < 4; i++) v[i] = -INFINITY;
    }
    #pragma unroll
    for (int i = 0; i < 4; i++){
      float cm = wred_max64(v[i]);
      float mn = fmaxf(m[i], cm);
      float e2 = act ? __expf(v[i] - mn) : 0.f;
      den[i] = den[i] * __expf(m[i] - mn) + wred_sum64(e2);
      m[i] = mn;
    }
  }

  float dninv[4];
  #pragma unroll
  for (int i = 0; i < 4; i++) dninv[i] = 1.f / fmaxf(den[i], 1e-16f);

  float acc0 = 0.f, acc1 = 0.f, acc2 = 0.f, acc3 = 0.f;
  float* q = sq[wv];

  auto accum = [&](int cnt){
    for (int e = 0; e < cnt; e++){
      float a  = q[e * 5 + head];
      int src  = __float_as_int(q[e * 5 + 4]);
      uint2 hv = *(reinterpret_cast<const uint2*>(h16 + ((size_t)src << 8)) + lane);
      float2 f0 = __half22float2(*reinterpret_cast<const __half2*>(&hv.x));
      float2 f1 = __half22float2(*reinterpret_cast<const __half2*>(&hv.y));
      acc0 += a * f0.x; acc1 += a * f0.y; acc2 += a * f1.x; acc3 += a * f1.y;
    }
  };

  if (deg <= 64){
    // fast path: chunk-0 ex already uses the final max
    #pragma unroll
    for (int i = 0; i < 4; i++) q[lane * 5 + i] = ex[i] * dninv[i];
    q[lane * 5 + 4] = __int_as_float(s);
    WAVE_SYNC();
    accum(deg);
  } else {
    for (int base = 0; base < deg; base += 64){
      const int k = base + lane;
      int s2 = 0; float al[4] = {0.f, 0.f, 0.f, 0.f};
      if (k < deg){
        s2 = csr[beg + k];
        float4 sl = reinterpret_cast<const float4*>(s_log)[s2];
        float t[4] = {sl.x, sl.y, sl.z, sl.w};
        #pragma unroll
        for (int i = 0; i < 4; i++){
          float u = t[i] + d4[i]; u = (u >= 0.f) ? u : NEG * u;
          al[i] = __expf(u - m[i]) * dninv[i];
        }
      }
      #pragma unroll
      for (int i = 0; i < 4; i++) q[lane * 5 + i] = al[i];
      q[lane * 5 + 4] = __int_as_float(s2);
      WAVE_SYNC();
      accum(min(64, deg - base));
      WAVE_SYNC();
    }
  }

  const float4 b4 = reinterpret_cast<const float4*>(bias)[lane];
  float4 o;
  o.x = acc0 + b4.x; o.y = acc1 + b4.y; o.z = acc2 + b4.z; o.w = acc3 + b4.w;
  reinterpret_cast<float4*>(out + ((size_t)n << 8))[lane] = o;
}

// out[n,c] = (relu?)(in[n,:]@w[:,c] + b[c]); in [N,256], w [256,64]
template<bool RELU>
__global__ __launch_bounds__(256)
void head_linear(const float* __restrict__ in, const float* __restrict__ w,
                 const float* __restrict__ b, float* __restrict__ out, int N)
{
  const int tid = threadIdx.x;
  const int n0 = blockIdx.x * 16;
  __shared__ float xs[16][GHC];  // 16 KB
  for (int idx = tid; idx < 16 * GHC; idx += 256){
    int nn = idx >> 8, j = idx & 255;
    int node = n0 + nn;
    xs[nn][j] = (node < N) ? in[(size_t)node * GHC + j] : 0.f;
  }
  __syncthreads();
  const int c = tid & 63, qd = tid >> 6;
  float acc[4] = {0.f, 0.f, 0.f, 0.f};
  for (int j = 0; j < GHC; j++){
    float wv = w[j * CH + c];
    #pragma unroll
    for (int i = 0; i < 4; i++) acc[i] += xs[qd * 4 + i][j] * wv;
  }
  const float bb = b[c];
  #pragma unroll
  for (int i = 0; i < 4; i++){
    int node = n0 + qd * 4 + i;
    if (node < N){
      float v = acc[i] + bb;
      if (RELU) v = fmaxf(v, 0.f);
      out[(size_t)node * CH + c] = v;
    }
  }
}

// ---------------- pooling + MLP head ----------------
__global__ __launch_bounds__(256)
void pool_kernel(const float* __restrict__ x3, const int* __restrict__ batch,
                 float* __restrict__ pS, int* __restrict__ pC, int N)
{
  int idx = blockIdx.x * 256 + threadIdx.x;
  int n = idx >> 6, c = idx & 63;
  if (n >= N) return;
  int g = batch[n];
  atomicAdd(&pS[g * CH + c], x3[(size_t)n * CH + c]);
  if (c == 0) atomicAdd(&pC[g], 1);
}

__global__ __launch_bounds__(256)
void mlp1_kernel(const float* __restrict__ pS, const int* __restrict__ pC,
                 const float* __restrict__ w, const float* __restrict__ b,
                 float* __restrict__ g1)
{
  int g = blockIdx.x;
  int tid = threadIdx.x;
  __shared__ float mean[CH];
  if (tid < CH){
    float cf = (float)max(pC[g], 1);
    mean[tid] = pS[g * CH + tid] / cf;
  }
  __syncthreads();
  float acc = b[tid];
  for (int c = 0; c < CH; c++) acc += mean[c] * w[c * 256 + tid];
  g1[g * 256 + tid] = fmaxf(acc, 0.f);
}

__global__ __launch_bounds__(256)
void mlp2_kernel(const float* __restrict__ g1, const float* __restrict__ w,
                 const float* __restrict__ b, float* __restrict__ out)
{
  int g = blockIdx.x;
  int tid = threadIdx.x;
  __shared__ float row[256];
  row[tid] = g1[g * 256 + tid];
  __syncthreads();
  float acc = b[tid];
  for (int k = 0; k < 256; k++) acc += row[k] * w[k * 256 + tid];
  out[g * 256 + tid] = acc;
}

// ---------------- launcher ----------------
extern "C" void kernel_launch(void* const* d_in, const int* in_sizes, int n_in,
                              void* d_out, int out_size, void* d_ws, size_t ws_size,
                              hipStream_t stream)
{
  const float* x     = (const float*)d_in[0];
  const int*   ei    = (const int*)d_in[1];
  const int*   batch = (const int*)d_in[2];
  const float* W1  = (const float*)d_in[4];
  const float* a1s = (const float*)d_in[5];
  const float* a1d = (const float*)d_in[6];
  const float* b1  = (const float*)d_in[7];
  const float* h1w = (const float*)d_in[8];
  const float* h1b = (const float*)d_in[9];
  const float* W2  = (const float*)d_in[10];
  const float* a2s = (const float*)d_in[11];
  const float* a2d = (const float*)d_in[12];
  const float* b2  = (const float*)d_in[13];
  const float* h2w = (const float*)d_in[14];
  const float* h2b = (const float*)d_in[15];
  const float* W3  = (const float*)d_in[16];
  const float* a3s = (const float*)d_in[17];
  const float* a3d = (const float*)d_in[18];
  const float* b3  = (const float*)d_in[19];
  const float* h3w = (const float*)d_in[20];
  const float* h3b = (const float*)d_in[21];
  const float* m1w = (const float*)d_in[22];
  const float* m1b = (const float*)d_in[23];
  const float* m2w = (const float*)d_in[24];
  const float* m2b = (const float*)d_in[25];

  const int N = in_sizes[0] / 32;
  const int E = in_sizes[1] / 2;
  const int G = out_size / 256;
  const int Etot = E + N;
  const int nb = (N + 255) / 256;

  char* p = (char*)d_ws;
  auto alloc = [&](size_t bytes) -> void* {
    void* r = (void*)p;
    p += ((bytes + 255) / 256) * 256;
    return r;
  };
  __half* buf_h  = (__half*)alloc((size_t)N * GHC * 2);
  float* buf_agg = (float*)alloc((size_t)N * GHC * 4);
  float* buf_x   = (float*)alloc((size_t)N * CH * 4);
  float* s_log   = (float*)alloc((size_t)N * HD * 4);
  float* d_log   = (float*)alloc((size_t)N * HD * 4);
  int*   counts  = (int*)alloc((size_t)N * 4);
  int*   offs    = (int*)alloc((size_t)(N + 1) * 4);
  int*   fill    = (int*)alloc((size_t)N * 4);
  int*   csr     = (int*)alloc((size_t)Etot * 4);
  int*   blkS    = (int*)alloc((size_t)nb * 4);
  int*   carry   = (int*)alloc((size_t)nb * 4);
  float* poolS   = (float*)alloc((size_t)G * CH * 4);
  int*   poolC   = (int*)alloc((size_t)G * 4);
  float* g1buf   = (float*)alloc((size_t)G * 256 * 4);

  hipMemsetAsync(counts, 0, (size_t)N * 4, stream);
  hipMemsetAsync(fill,   0, (size_t)N * 4, stream);
  hipMemsetAsync(poolS,  0, (size_t)G * CH * 4, stream);
  hipMemsetAsync(poolC,  0, (size_t)G * 4, stream);

  count_deg<<<(Etot + 255) / 256, 256, 0, stream>>>(ei, E, N, counts);
  scan_local<<<nb, 256, 0, stream>>>(counts, N, offs, blkS);
  scan_carry<<<1, 256, 0, stream>>>(blkS, nb, carry);
  scan_add<<<nb, 256, 0, stream>>>(offs, carry, N, Etot);
  fill_csr<<<(Etot + 255) / 256, 256, 0, stream>>>(ei, E, N, offs, fill, csr);

  const int gb = (N + 15) / 16;
  const int ab = (N + 3) / 4;

  feat_gemm<32><<<gb, 256, 0, stream>>>(x, W1, a1s, a1d, buf_h, s_log, d_log, N);
  gat_aggregate<<<ab, 256, 0, stream>>>(buf_h, s_log, d_log, offs, csr, b1, buf_agg, N);
  head_linear<true><<<gb, 256, 0, stream>>>(buf_agg, h1w, h1b, buf_x, N);

  feat_gemm<64><<<gb, 256, 0, stream>>>(buf_x, W2, a2s, a2d, buf_h, s_log, d_log, N);
  gat_aggregate<<<ab, 256, 0, stream>>>(buf_h, s_log, d_log, offs, csr, b2, buf_agg, N);
  head_linear<true><<<gb, 256, 0, stream>>>(buf_agg, h2w, h2b, buf_x, N);

  feat_gemm<64><<<gb, 256, 0, stream>>>(buf_x, W3, a3s, a3d, buf_h, s_log, d_log, N);
  gat_aggregate<<<ab, 256, 0, stream>>>(buf_h, s_log, d_log, offs, csr, b3, buf_agg, N);
  head_linear<false><<<gb, 256, 0, stream>>>(buf_agg, h3w, h3b, buf_x, N);

  pool_kernel<<<((size_t)N * CH + 255) / 256, 256, 0, stream>>>(buf_x, batch, poolS, poolC, N);
  mlp1_kernel<<<G, 256, 0, stream>>>(poolS, poolC, m1w, m1b, g1buf);
  mlp2_kernel<<<G, 256, 0, stream>>>(g1buf, m2w, m2b, (float*)d_out);
}

// Round 3
// 638.182 us; speedup vs baseline: 1.6958x; 1.1684x over previous
//
#include <hip/hip_runtime.h>
#include <hip/hip_bf16.h>
#include <hip/hip_fp16.h>
#include <math.h>

#define HD 4
#define CH 64
#define GHC 256
#define NEG 0.2f

#define WAVE_SYNC() do { __builtin_amdgcn_wave_barrier(); \
                         asm volatile("s_waitcnt lgkmcnt(0)" ::: "memory"); } while (0)

__device__ __forceinline__ float wred_sum_down(float v){
  #pragma unroll
  for (int o = 32; o > 0; o >>= 1) v += __shfl_down(v, o);
  return v;
}
__device__ __forceinline__ float wred_sum64(float v){
  #pragma unroll
  for (int o = 32; o > 0; o >>= 1) v += __shfl_xor(v, o);
  return v;
}
__device__ __forceinline__ float wred_max64(float v){
  #pragma unroll
  for (int o = 32; o > 0; o >>= 1) v = fmaxf(v, __shfl_xor(v, o));
  return v;
}

// ---------------- CSR build ----------------
__global__ __launch_bounds__(256)
void count_deg(const int* __restrict__ ei, int E, int N, int* __restrict__ cnt){
  int i = blockIdx.x * 256 + threadIdx.x;
  int tot = E + N;
  if (i >= tot) return;
  int dst = (i < E) ? ei[E + i] : (i - E);
  atomicAdd(&cnt[dst], 1);
}

__global__ __launch_bounds__(256)
void scan_local(const int* __restrict__ cnt, int N, int* __restrict__ off, int* __restrict__ blkS){
  __shared__ int sh[256];
  int tid = threadIdx.x;
  int i = blockIdx.x * 256 + tid;
  int v = (i < N) ? cnt[i] : 0;
  sh[tid] = v;
  __syncthreads();
  for (int o = 1; o < 256; o <<= 1){
    int t = (tid >= o) ? sh[tid - o] : 0;
    __syncthreads();
    sh[tid] += t;
    __syncthreads();
  }
  if (i < N) off[i] = sh[tid] - v;      // exclusive within block
  if (tid == 255) blkS[blockIdx.x] = sh[255];
}

__global__ __launch_bounds__(256)
void scan_carry(const int* __restrict__ blkS, int nb, int* __restrict__ carry){
  __shared__ int sh[256];
  int tid = threadIdx.x;
  int v = (tid < nb) ? blkS[tid] : 0;   // requires nb <= 256 (N=50000 -> nb=196)
  sh[tid] = v;
  __syncthreads();
  for (int o = 1; o < 256; o <<= 1){
    int t = (tid >= o) ? sh[tid - o] : 0;
    __syncthreads();
    sh[tid] += t;
    __syncthreads();
  }
  if (tid < nb) carry[tid] = sh[tid] - v;
}

__global__ __launch_bounds__(256)
void scan_add(int* __restrict__ off, const int* __restrict__ carry, int N, int Etot){
  int i = blockIdx.x * 256 + threadIdx.x;
  if (i < N) off[i] += carry[blockIdx.x];
  if (i == 0) off[N] = Etot;
}

__global__ __launch_bounds__(256)
void fill_csr(const int* __restrict__ ei, int E, int N, const int* __restrict__ off,
              int* __restrict__ fill, int* __restrict__ csr){
  int i = blockIdx.x * 256 + threadIdx.x;
  int tot = E + N;
  if (i >= tot) return;
  int src, dst;
  if (i < E){ src = ei[i]; dst = ei[E + i]; }
  else { src = dst = i - E; }
  int pos = off[dst] + atomicAdd(&fill[dst], 1);
  csr[pos] = src;
}

// ---------------- per-layer kernels ----------------
// h = x @ W ([N,FIN]@[FIN,256]) -> fp16; fused attention logits s,d ([N,4]).
template<int FIN>
__global__ __launch_bounds__(256)
void feat_gemm(const float* __restrict__ x, const float* __restrict__ W,
               const float* __restrict__ a_s, const float* __restrict__ a_d,
               __half* __restrict__ h, float* __restrict__ s_log, float* __restrict__ d_log,
               int N)
{
  const int tid = threadIdx.x;
  const int n0 = blockIdx.x * 16;
  __shared__ float xs[16][FIN];
  for (int idx = tid; idx < 16 * FIN; idx += 256){
    int nn = idx / FIN, k = idx % FIN;
    int node = n0 + nn;
    xs[nn][k] = (node < N) ? x[(size_t)node * FIN + k] : 0.f;
  }
  __syncthreads();
  float acc[16];
  #pragma unroll
  for (int i = 0; i < 16; i++) acc[i] = 0.f;
  #pragma unroll 4
  for (int k = 0; k < FIN; k++){
    float wv = W[k * GHC + tid];
    #pragma unroll
    for (int nn = 0; nn < 16; nn++) acc[nn] += xs[nn][k] * wv;
  }
  const float as = a_s[tid], ad = a_d[tid];
  const int hd = tid >> 6, ln = tid & 63;
  #pragma unroll
  for (int nn = 0; nn < 16; nn++){
    int node = n0 + nn;
    if (node < N){
      h[(size_t)node * GHC + tid] = __float2half(acc[nn]);
      float vs = wred_sum_down(acc[nn] * as);
      float vd = wred_sum_down(acc[nn] * ad);
      if (ln == 0){ s_log[node * HD + hd] = vs; d_log[node * HD + hd] = vd; }
    }
  }
}

// One WAVE per destination node: segment softmax + weighted gather-sum.
// lane owns channels [4*lane .. 4*lane+3]; head = lane>>4.
__global__ __launch_bounds__(256)
void gat_aggregate(const __half* __restrict__ h16, const float* __restrict__ s_log,
                   const float* __restrict__ d_log, const int* __restrict__ off,
                   const int* __restrict__ csr, const float* __restrict__ bias,
                   float* __restrict__ out, int N)
{
  __shared__ float sq[4][64 * 5];   // per-wave: 64 edges x {alpha0..3, src}
  const int wv   = threadIdx.x >> 6;
  const int lane = threadIdx.x & 63;
  const int n = blockIdx.x * 4 + wv;
  if (n >= N) return;
  const int head = lane >> 4;
  const int beg = off[n];
  const int deg = off[n + 1] - beg;

  const float4 d4v = reinterpret_cast<const float4*>(d_log)[n];
  const float d4[4] = {d4v.x, d4v.y, d4v.z, d4v.w};

  float m[4], den[4], ex[4];
  int s = 0;

  // ---- chunk 0 softmax stats (always) ----
  {
    const int k = lane;
    const bool act = k < deg;
    float v[4];
    if (act){
      s = csr[beg + k];
      float4 sl = reinterpret_cast<const float4*>(s_log)[s];
      float t[4] = {sl.x, sl.y, sl.z, sl.w};
      #pragma unroll
      for (int i = 0; i < 4; i++){ float u = t[i] + d4[i]; v[i] = (u >= 0.f) ? u : NEG * u; }
    } else {
      #pragma unroll
      for (int i = 0; i < 4; i++) v[i] = -INFINITY;
    }
    #pragma unroll
    for (int i = 0; i < 4; i++){
      m[i] = wred_max64(v[i]);
      ex[i] = act ? __expf(v[i] - m[i]) : 0.f;
      den[i] = wred_sum64(ex[i]);
    }
  }
  // ---- remaining chunks (rare: deg > 64), online rescale ----
  for (int base = 64; base < deg; base += 64){
    const int k = base + lane;
    const bool act = k < deg;
    float v[4]; int s2 = 0;
    if (act){
      s2 = csr[beg + k];
      float4 sl = reinterpret_cast<const float4*>(s_log)[s2];
      float t[4] = {sl.x, sl.y, sl.z, sl.w};
      #pragma unroll
      for (int i = 0; i < 4; i++){ float u = t[i] + d4[i]; v[i] = (u >= 0.f) ? u : NEG * u; }
    } else {
      #pragma unroll
      for (int i = 0; i < 4; i++) v[i] = -INFINITY;
    }
    #pragma unroll
    for (int i = 0; i < 4; i++){
      float cm = wred_max64(v[i]);
      float mn = fmaxf(m[i], cm);
      float e2 = act ? __expf(v[i] - mn) : 0.f;
      den[i] = den[i] * __expf(m[i] - mn) + wred_sum64(e2);
      m[i] = mn;
    }
  }

  float dninv[4];
  #pragma unroll
  for (int i = 0; i < 4; i++) dninv[i] = 1.f / fmaxf(den[i], 1e-16f);

  float acc0 = 0.f, acc1 = 0.f, acc2 = 0.f, acc3 = 0.f;
  float* q = sq[wv];

  auto accum = [&](int cnt){
    for (int e = 0; e < cnt; e++){
      float a  = q[e * 5 + head];
      int src  = __float_as_int(q[e * 5 + 4]);
      uint2 hv = *(reinterpret_cast<const uint2*>(h16 + ((size_t)src << 8)) + lane);
      float2 f0 = __half22float2(*reinterpret_cast<const __half2*>(&hv.x));
      float2 f1 = __half22float2(*reinterpret_cast<const __half2*>(&hv.y));
      acc0 += a * f0.x; acc1 += a * f0.y; acc2 += a * f1.x; acc3 += a * f1.y;
    }
  };

  if (deg <= 64){
    // fast path: chunk-0 ex already uses the final max
    #pragma unroll
    for (int i = 0; i < 4; i++) q[lane * 5 + i] = ex[i] * dninv[i];
    q[lane * 5 + 4] = __int_as_float(s);
    WAVE_SYNC();
    accum(deg);
  } else {
    for (int base = 0; base < deg; base += 64){
      const int k = base + lane;
      int s2 = 0; float al[4] = {0.f, 0.f, 0.f, 0.f};
      if (k < deg){
        s2 = csr[beg + k];
        float4 sl = reinterpret_cast<const float4*>(s_log)[s2];
        float t[4] = {sl.x, sl.y, sl.z, sl.w};
        #pragma unroll
        for (int i = 0; i < 4; i++){
          float u = t[i] + d4[i]; u = (u >= 0.f) ? u : NEG * u;
          al[i] = __expf(u - m[i]) * dninv[i];
        }
      }
      #pragma unroll
      for (int i = 0; i < 4; i++) q[lane * 5 + i] = al[i];
      q[lane * 5 + 4] = __int_as_float(s2);
      WAVE_SYNC();
      accum(min(64, deg - base));
      WAVE_SYNC();
    }
  }

  const float4 b4 = reinterpret_cast<const float4*>(bias)[lane];
  float4 o;
  o.x = acc0 + b4.x; o.y = acc1 + b4.y; o.z = acc2 + b4.z; o.w = acc3 + b4.w;
  reinterpret_cast<float4*>(out + ((size_t)n << 8))[lane] = o;
}

// out[n,c] = (relu?)(in[n,:]@w[:,c] + b[c]); in [N,256], w [256,64]
template<bool RELU>
__global__ __launch_bounds__(256)
void head_linear(const float* __restrict__ in, const float* __restrict__ w,
                 const float* __restrict__ b, float* __restrict__ out, int N)
{
  const int tid = threadIdx.x;
  const int n0 = blockIdx.x * 16;
  __shared__ float xs[16][GHC];  // 16 KB
  for (int idx = tid; idx < 16 * GHC; idx += 256){
    int nn = idx >> 8, j = idx & 255;
    int node = n0 + nn;
    xs[nn][j] = (node < N) ? in[(size_t)node * GHC + j] : 0.f;
  }
  __syncthreads();
  const int c = tid & 63, qd = tid >> 6;
  float acc[4] = {0.f, 0.f, 0.f, 0.f};
  for (int j = 0; j < GHC; j++){
    float wv = w[j * CH + c];
    #pragma unroll
    for (int i = 0; i < 4; i++) acc[i] += xs[qd * 4 + i][j] * wv;
  }
  const float bb = b[c];
  #pragma unroll
  for (int i = 0; i < 4; i++){
    int node = n0 + qd * 4 + i;
    if (node < N){
      float v = acc[i] + bb;
      if (RELU) v = fmaxf(v, 0.f);
      out[(size_t)node * CH + c] = v;
    }
  }
}

// ---------------- pooling + MLP head ----------------
// bnd[g] = first node of graph g (batch is sorted); bnd[G] = N.
__global__ __launch_bounds__(256)
void graph_bounds(const int* __restrict__ batch, int N, int G, int* __restrict__ bnd){
  int g = blockIdx.x * 256 + threadIdx.x;
  if (g > G) return;
  if (g == G){ bnd[G] = N; return; }
  int lo = 0, hi = N;
  while (lo < hi){ int mid = (lo + hi) >> 1; if (batch[mid] < g) lo = mid + 1; else hi = mid; }
  bnd[g] = lo;
}

// one block per graph: mean over its node range, then fused mlp1 (relu).
__global__ __launch_bounds__(256)
void pool_mlp1(const float* __restrict__ x3, const int* __restrict__ bnd,
               const float* __restrict__ w, const float* __restrict__ b,
               float* __restrict__ g1)
{
  const int g = blockIdx.x;
  const int tid = threadIdx.x;
  const int s = bnd[g], e = bnd[g + 1];
  const int c = tid & 63, j = tid >> 6;
  float acc = 0.f;
  for (int n = s + j; n < e; n += 4)
    acc += x3[(size_t)n * CH + c];
  __shared__ float sh[4][CH];
  __shared__ float mean[CH];
  sh[j][c] = acc;
  __syncthreads();
  if (tid < CH){
    float cnt = (float)max(e - s, 1);
    mean[tid] = (sh[0][tid] + sh[1][tid] + sh[2][tid] + sh[3][tid]) / cnt;
  }
  __syncthreads();
  float a = b[tid];
  #pragma unroll 8
  for (int cc = 0; cc < CH; cc++) a += mean[cc] * w[cc * 256 + tid];
  g1[g * 256 + tid] = fmaxf(a, 0.f);
}

__global__ __launch_bounds__(256)
void mlp2_kernel(const float* __restrict__ g1, const float* __restrict__ w,
                 const float* __restrict__ b, float* __restrict__ out)
{
  int g = blockIdx.x;
  int tid = threadIdx.x;
  __shared__ float row[256];
  row[tid] = g1[g * 256 + tid];
  __syncthreads();
  float acc = b[tid];
  for (int k = 0; k < 256; k++) acc += row[k] * w[k * 256 + tid];
  out[g * 256 + tid] = acc;
}

// ---------------- launcher ----------------
extern "C" void kernel_launch(void* const* d_in, const int* in_sizes, int n_in,
                              void* d_out, int out_size, void* d_ws, size_t ws_size,
                              hipStream_t stream)
{
  const float* x     = (const float*)d_in[0];
  const int*   ei    = (const int*)d_in[1];
  const int*   batch = (const int*)d_in[2];
  const float* W1  = (const float*)d_in[4];
  const float* a1s = (const float*)d_in[5];
  const float* a1d = (const float*)d_in[6];
  const float* b1  = (const float*)d_in[7];
  const float* h1w = (const float*)d_in[8];
  const float* h1b = (const float*)d_in[9];
  const float* W2  = (const float*)d_in[10];
  const float* a2s = (const float*)d_in[11];
  const float* a2d = (const float*)d_in[12];
  const float* b2  = (const float*)d_in[13];
  const float* h2w = (const float*)d_in[14];
  const float* h2b = (const float*)d_in[15];
  const float* W3  = (const float*)d_in[16];
  const float* a3s = (const float*)d_in[17];
  const float* a3d = (const float*)d_in[18];
  const float* b3  = (const float*)d_in[19];
  const float* h3w = (const float*)d_in[20];
  const float* h3b = (const float*)d_in[21];
  const float* m1w = (const float*)d_in[22];
  const float* m1b = (const float*)d_in[23];
  const float* m2w = (const float*)d_in[24];
  const float* m2b = (const float*)d_in[25];

  const int N = in_sizes[0] / 32;
  const int E = in_sizes[1] / 2;
  const int G = out_size / 256;
  const int Etot = E + N;
  const int nb = (N + 255) / 256;

  char* p = (char*)d_ws;
  auto alloc = [&](size_t bytes) -> void* {
    void* r = (void*)p;
    p += ((bytes + 255) / 256) * 256;
    return r;
  };
  __half* buf_h  = (__half*)alloc((size_t)N * GHC * 2);
  float* buf_agg = (float*)alloc((size_t)N * GHC * 4);
  float* buf_x   = (float*)alloc((size_t)N * CH * 4);
  float* s_log   = (float*)alloc((size_t)N * HD * 4);
  float* d_log   = (float*)alloc((size_t)N * HD * 4);
  int*   counts  = (int*)alloc((size_t)N * 4);
  int*   offs    = (int*)alloc((size_t)(N + 1) * 4);
  int*   fill    = (int*)alloc((size_t)N * 4);
  int*   csr     = (int*)alloc((size_t)Etot * 4);
  int*   blkS    = (int*)alloc((size_t)nb * 4);
  int*   carry   = (int*)alloc((size_t)nb * 4);
  int*   bnd     = (int*)alloc((size_t)(G + 1) * 4);
  float* g1buf   = (float*)alloc((size_t)G * 256 * 4);

  hipMemsetAsync(counts, 0, (size_t)N * 4, stream);
  hipMemsetAsync(fill,   0, (size_t)N * 4, stream);

  count_deg<<<(Etot + 255) / 256, 256, 0, stream>>>(ei, E, N, counts);
  scan_local<<<nb, 256, 0, stream>>>(counts, N, offs, blkS);
  scan_carry<<<1, 256, 0, stream>>>(blkS, nb, carry);
  scan_add<<<nb, 256, 0, stream>>>(offs, carry, N, Etot);
  fill_csr<<<(Etot + 255) / 256, 256, 0, stream>>>(ei, E, N, offs, fill, csr);
  graph_bounds<<<(G + 256) / 256, 256, 0, stream>>>(batch, N, G, bnd);

  const int gb = (N + 15) / 16;
  const int ab = (N + 3) / 4;

  feat_gemm<32><<<gb, 256, 0, stream>>>(x, W1, a1s, a1d, buf_h, s_log, d_log, N);
  gat_aggregate<<<ab, 256, 0, stream>>>(buf_h, s_log, d_log, offs, csr, b1, buf_agg, N);
  head_linear<true><<<gb, 256, 0, stream>>>(buf_agg, h1w, h1b, buf_x, N);

  feat_gemm<64><<<gb, 256, 0, stream>>>(buf_x, W2, a2s, a2d, buf_h, s_log, d_log, N);
  gat_aggregate<<<ab, 256, 0, stream>>>(buf_h, s_log, d_log, offs, csr, b2, buf_agg, N);
  head_linear<true><<<gb, 256, 0, stream>>>(buf_agg, h2w, h2b, buf_x, N);

  feat_gemm<64><<<gb, 256, 0, stream>>>(buf_x, W3, a3s, a3d, buf_h, s_log, d_log, N);
  gat_aggregate<<<ab, 256, 0, stream>>>(buf_h, s_log, d_log, offs, csr, b3, buf_agg, N);
  head_linear<false><<<gb, 256, 0, stream>>>(buf_agg, h3w, h3b, buf_x, N);

  pool_mlp1<<<G, 256, 0, stream>>>(buf_x, bnd, m1w, m1b, g1buf);
  mlp2_kernel<<<G, 256, 0, stream>>>(g1buf, m2w, m2b, (float*)d_out);
}

// Round 4
// 454.484 us; speedup vs baseline: 2.3812x; 1.4042x over previous
//
#include <hip/hip_runtime.h>
#include <hip/hip_bf16.h>
#include <hip/hip_fp16.h>
#include <math.h>

#define HD 4
#define CH 64
#define GHC 256
#define NEG 0.2f

#define WAVE_SYNC() do { __builtin_amdgcn_wave_barrier(); \
                         asm volatile("s_waitcnt lgkmcnt(0)" ::: "memory"); } while (0)

__device__ __forceinline__ float wred_sum64(float v){
  #pragma unroll
  for (int o = 32; o > 0; o >>= 1) v += __shfl_xor(v, o);
  return v;
}
__device__ __forceinline__ float wred_max64(float v){
  #pragma unroll
  for (int o = 32; o > 0; o >>= 1) v = fmaxf(v, __shfl_xor(v, o));
  return v;
}

// ---------------- CSR build ----------------
__global__ __launch_bounds__(256)
void count_deg(const int* __restrict__ ei, int E, int N, int* __restrict__ cnt){
  int i = blockIdx.x * 256 + threadIdx.x;
  int tot = E + N;
  if (i >= tot) return;
  int dst = (i < E) ? ei[E + i] : (i - E);
  atomicAdd(&cnt[dst], 1);
}

__global__ __launch_bounds__(256)
void scan_local(const int* __restrict__ cnt, int N, int* __restrict__ off, int* __restrict__ blkS){
  __shared__ int sh[256];
  int tid = threadIdx.x;
  int i = blockIdx.x * 256 + tid;
  int v = (i < N) ? cnt[i] : 0;
  sh[tid] = v;
  __syncthreads();
  for (int o = 1; o < 256; o <<= 1){
    int t = (tid >= o) ? sh[tid - o] : 0;
    __syncthreads();
    sh[tid] += t;
    __syncthreads();
  }
  if (i < N) off[i] = sh[tid] - v;      // exclusive within block
  if (tid == 255) blkS[blockIdx.x] = sh[255];
}

__global__ __launch_bounds__(256)
void scan_carry(const int* __restrict__ blkS, int nb, int* __restrict__ carry){
  __shared__ int sh[256];
  int tid = threadIdx.x;
  int v = (tid < nb) ? blkS[tid] : 0;   // requires nb <= 256 (N=50000 -> nb=196)
  sh[tid] = v;
  __syncthreads();
  for (int o = 1; o < 256; o <<= 1){
    int t = (tid >= o) ? sh[tid - o] : 0;
    __syncthreads();
    sh[tid] += t;
    __syncthreads();
  }
  if (tid < nb) carry[tid] = sh[tid] - v;
}

__global__ __launch_bounds__(256)
void scan_add(int* __restrict__ off, const int* __restrict__ carry, int N, int Etot){
  int i = blockIdx.x * 256 + threadIdx.x;
  if (i < N) off[i] += carry[blockIdx.x];
  if (i == 0) off[N] = Etot;
}

__global__ __launch_bounds__(256)
void fill_csr(const int* __restrict__ ei, int E, int N, const int* __restrict__ off,
              int* __restrict__ fill, int* __restrict__ csr){
  int i = blockIdx.x * 256 + threadIdx.x;
  int tot = E + N;
  if (i >= tot) return;
  int src, dst;
  if (i < E){ src = ei[i]; dst = ei[E + i]; }
  else { src = dst = i - E; }
  int pos = off[dst] + atomicAdd(&fill[dst], 1);
  csr[pos] = src;
}

// ---------------- fused-weight precompute (per layer) ----------------
// Wc[k][c*4+h] = sum_j W[k][h*64+j] * hlw[h*64+j][c]          [FIN x 256]
// Psd[k][h]    = sum_j W[k][h*64+j] * a_s[h][j]  (h<4: src; h>=4: dst)
// cb[c]        = hlb[c] + sum_j bl[j] * hlw[j][c]
__global__ __launch_bounds__(256)
void fuse_weights(const float* __restrict__ W, const float* __restrict__ as,
                  const float* __restrict__ ad, const float* __restrict__ bl,
                  const float* __restrict__ hlw, const float* __restrict__ hlb,
                  int FIN, float* __restrict__ Wc, float* __restrict__ Psd,
                  float* __restrict__ cb)
{
  const int b = blockIdx.x, t = threadIdx.x;
  if (b < FIN){
    const int c = t >> 2, h = t & 3;
    const float* wrow = W + b * GHC + h * 64;
    float acc = 0.f;
    #pragma unroll 8
    for (int j = 0; j < 64; j++)
      acc += wrow[j] * hlw[(h * 64 + j) * CH + c];
    Wc[b * GHC + t] = acc;
    if (t < 8){
      const int hh = t & 3;
      const float* a = (t < 4) ? as : ad;
      const float* wr2 = W + b * GHC + hh * 64;
      float p = 0.f;
      #pragma unroll 8
      for (int j = 0; j < 64; j++) p += wr2[j] * a[hh * 64 + j];
      Psd[b * 8 + t] = p;
    }
  } else if (t < CH){
    float acc = hlb[t];
    for (int j = 0; j < GHC; j++) acc += bl[j] * hlw[j * CH + t];
    cb[t] = acc;
  }
}

// ---------------- per-layer kernels ----------------
// h'[n, c*4+h] = x @ Wc (fp16, interleaved by head); logits = x @ Psd.
template<int FIN>
__global__ __launch_bounds__(256)
void feat_gemm(const float* __restrict__ x, const float* __restrict__ Wc,
               const float* __restrict__ Psd,
               __half* __restrict__ h, float* __restrict__ s_log, float* __restrict__ d_log,
               int N)
{
  const int tid = threadIdx.x;
  const int n0 = blockIdx.x * 16;
  __shared__ float xs[16][FIN];
  __shared__ float ps[FIN][8];
  for (int idx = tid; idx < 16 * FIN; idx += 256){
    int nn = idx / FIN, k = idx % FIN;
    int node = n0 + nn;
    xs[nn][k] = (node < N) ? x[(size_t)node * FIN + k] : 0.f;
  }
  for (int idx = tid; idx < FIN * 8; idx += 256)
    ps[idx >> 3][idx & 7] = Psd[idx];
  __syncthreads();
  float acc[16];
  #pragma unroll
  for (int i = 0; i < 16; i++) acc[i] = 0.f;
  #pragma unroll 4
  for (int k = 0; k < FIN; k++){
    float wv = Wc[k * GHC + tid];
    #pragma unroll
    for (int nn = 0; nn < 16; nn++) acc[nn] += xs[nn][k] * wv;
  }
  #pragma unroll
  for (int nn = 0; nn < 16; nn++){
    int node = n0 + nn;
    if (node < N) h[(size_t)node * GHC + tid] = __float2half(acc[nn]);
  }
  if (tid < 128){
    const int nn = tid >> 3, q = tid & 7;
    const int node = n0 + nn;
    if (node < N){
      float v = 0.f;
      #pragma unroll 8
      for (int k = 0; k < FIN; k++) v += xs[nn][k] * ps[k][q];
      if (q < 4) s_log[node * 4 + q]       = v;
      else       d_log[node * 4 + (q - 4)] = v;
    }
  }
}

// One WAVE per destination node. lane = output channel c (0..63);
// per edge, lane reads 4 halves h'_{head0..3}[c] (uint2) and does 4 FMA.
// Epilogue fuses head-linear bias + optional relu.
template<bool RELU>
__global__ __launch_bounds__(256)
void gat_aggregate(const __half* __restrict__ h16, const float* __restrict__ s_log,
                   const float* __restrict__ d_log, const int* __restrict__ off,
                   const int* __restrict__ csr, const float* __restrict__ cb,
                   float* __restrict__ out, int N)
{
  __shared__ float4 qa[4][64];
  __shared__ int    qs[4][64];
  const int wv   = threadIdx.x >> 6;
  const int lane = threadIdx.x & 63;
  const int n = blockIdx.x * 4 + wv;
  if (n >= N) return;
  const int beg = off[n];
  const int deg = off[n + 1] - beg;

  const float4 d4v = reinterpret_cast<const float4*>(d_log)[n];
  const float d4[4] = {d4v.x, d4v.y, d4v.z, d4v.w};

  float m[4], den[4], ex[4];
  int s = 0;

  // ---- chunk 0 softmax stats ----
  {
    const bool act = lane < deg;
    float v[4];
    if (act){
      s = csr[beg + lane];
      float4 sl = reinterpret_cast<const float4*>(s_log)[s];
      float t[4] = {sl.x, sl.y, sl.z, sl.w};
      #pragma unroll
      for (int i = 0; i < 4; i++){ float u = t[i] + d4[i]; v[i] = (u >= 0.f) ? u : NEG * u; }
    } else {
      #pragma unroll
      for (int i = 0; i < 4; i++) v[i] = -INFINITY;
    }
    #pragma unroll
    for (int i = 0; i < 4; i++){
      m[i] = wred_max64(v[i]);
      ex[i] = act ? __expf(v[i] - m[i]) : 0.f;
      den[i] = wred_sum64(ex[i]);
    }
  }
  // ---- remaining chunks (rare: deg > 64), online rescale ----
  for (int base = 64; base < deg; base += 64){
    const int k = base + lane;
    const bool act = k < deg;
    float v[4];
    if (act){
      int s2 = csr[beg + k];
      float4 sl = reinterpret_cast<const float4*>(s_log)[s2];
      float t[4] = {sl.x, sl.y, sl.z, sl.w};
      #pragma unroll
      for (int i = 0; i < 4; i++){ float u = t[i] + d4[i]; v[i] = (u >= 0.f) ? u : NEG * u; }
    } else {
      #pragma unroll
      for (int i = 0; i < 4; i++) v[i] = -INFINITY;
    }
    #pragma unroll
    for (int i = 0; i < 4; i++){
      float cm = wred_max64(v[i]);
      float mn = fmaxf(m[i], cm);
      float e2 = act ? __expf(v[i] - mn) : 0.f;
      den[i] = den[i] * __expf(m[i] - mn) + wred_sum64(e2);
      m[i] = mn;
    }
  }

  float dninv[4];
  #pragma unroll
  for (int i = 0; i < 4; i++) dninv[i] = 1.f / fmaxf(den[i], 1e-16f);

  float acc = 0.f;

  auto accum = [&](int cnt){
    for (int e = 0; e < cnt; e++){
      float4 a = qa[wv][e];
      int src  = qs[wv][e];
      uint2 hv = *(reinterpret_cast<const uint2*>(h16 + ((size_t)src << 8)) + lane);
      float2 f0 = __half22float2(*reinterpret_cast<const __half2*>(&hv.x));
      float2 f1 = __half22float2(*reinterpret_cast<const __half2*>(&hv.y));
      acc += a.x * f0.x + a.y * f0.y + a.z * f1.x + a.w * f1.y;
    }
  };

  if (deg <= 64){
    qa[wv][lane] = make_float4(ex[0] * dninv[0], ex[1] * dninv[1],
                               ex[2] * dninv[2], ex[3] * dninv[3]);
    qs[wv][lane] = s;
    WAVE_SYNC();
    accum(deg);
  } else {
    for (int base = 0; base < deg; base += 64){
      const int k = base + lane;
      int s2 = 0; float al[4] = {0.f, 0.f, 0.f, 0.f};
      if (k < deg){
        s2 = csr[beg + k];
        float4 sl = reinterpret_cast<const float4*>(s_log)[s2];
        float t[4] = {sl.x, sl.y, sl.z, sl.w};
        #pragma unroll
        for (int i = 0; i < 4; i++){
          float u = t[i] + d4[i]; u = (u >= 0.f) ? u : NEG * u;
          al[i] = __expf(u - m[i]) * dninv[i];
        }
      }
      qa[wv][lane] = make_float4(al[0], al[1], al[2], al[3]);
      qs[wv][lane] = s2;
      WAVE_SYNC();
      accum(min(64, deg - base));
      WAVE_SYNC();
    }
  }

  float o = acc + cb[lane];
  if (RELU) o = fmaxf(o, 0.f);
  out[(size_t)n * CH + lane] = o;
}

// ---------------- pooling + MLP head ----------------
__global__ __launch_bounds__(256)
void graph_bounds(const int* __restrict__ batch, int N, int G, int* __restrict__ bnd){
  int g = blockIdx.x * 256 + threadIdx.x;
  if (g > G) return;
  if (g == G){ bnd[G] = N; return; }
  int lo = 0, hi = N;
  while (lo < hi){ int mid = (lo + hi) >> 1; if (batch[mid] < g) lo = mid + 1; else hi = mid; }
  bnd[g] = lo;
}

__global__ __launch_bounds__(256)
void pool_mlp1(const float* __restrict__ x3, const int* __restrict__ bnd,
               const float* __restrict__ w, const float* __restrict__ b,
               float* __restrict__ g1)
{
  const int g = blockIdx.x;
  const int tid = threadIdx.x;
  const int s = bnd[g], e = bnd[g + 1];
  const int c = tid & 63, j = tid >> 6;
  float acc = 0.f;
  for (int n = s + j; n < e; n += 4)
    acc += x3[(size_t)n * CH + c];
  __shared__ float sh[4][CH];
  __shared__ float mean[CH];
  sh[j][c] = acc;
  __syncthreads();
  if (tid < CH){
    float cnt = (float)max(e - s, 1);
    mean[tid] = (sh[0][tid] + sh[1][tid] + sh[2][tid] + sh[3][tid]) / cnt;
  }
  __syncthreads();
  float a = b[tid];
  #pragma unroll 8
  for (int cc = 0; cc < CH; cc++) a += mean[cc] * w[cc * 256 + tid];
  g1[g * 256 + tid] = fmaxf(a, 0.f);
}

__global__ __launch_bounds__(256)
void mlp2_kernel(const float* __restrict__ g1, const float* __restrict__ w,
                 const float* __restrict__ b, float* __restrict__ out)
{
  int g = blockIdx.x;
  int tid = threadIdx.x;
  __shared__ float row[256];
  row[tid] = g1[g * 256 + tid];
  __syncthreads();
  float acc = b[tid];
  for (int k = 0; k < 256; k++) acc += row[k] * w[k * 256 + tid];
  out[g * 256 + tid] = acc;
}

// ---------------- launcher ----------------
extern "C" void kernel_launch(void* const* d_in, const int* in_sizes, int n_in,
                              void* d_out, int out_size, void* d_ws, size_t ws_size,
                              hipStream_t stream)
{
  const float* x     = (const float*)d_in[0];
  const int*   ei    = (const int*)d_in[1];
  const int*   batch = (const int*)d_in[2];
  const float* W1  = (const float*)d_in[4];
  const float* a1s = (const float*)d_in[5];
  const float* a1d = (const float*)d_in[6];
  const float* b1  = (const float*)d_in[7];
  const float* h1w = (const float*)d_in[8];
  const float* h1b = (const float*)d_in[9];
  const float* W2  = (const float*)d_in[10];
  const float* a2s = (const float*)d_in[11];
  const float* a2d = (const float*)d_in[12];
  const float* b2  = (const float*)d_in[13];
  const float* h2w = (const float*)d_in[14];
  const float* h2b = (const float*)d_in[15];
  const float* W3  = (const float*)d_in[16];
  const float* a3s = (const float*)d_in[17];
  const float* a3d = (const float*)d_in[18];
  const float* b3  = (const float*)d_in[19];
  const float* h3w = (const float*)d_in[20];
  const float* h3b = (const float*)d_in[21];
  const float* m1w = (const float*)d_in[22];
  const float* m1b = (const float*)d_in[23];
  const float* m2w = (const float*)d_in[24];
  const float* m2b = (const float*)d_in[25];

  const int N = in_sizes[0] / 32;
  const int E = in_sizes[1] / 2;
  const int G = out_size / 256;
  const int Etot = E + N;
  const int nb = (N + 255) / 256;

  char* p = (char*)d_ws;
  auto alloc = [&](size_t bytes) -> void* {
    void* r = (void*)p;
    p += ((bytes + 255) / 256) * 256;
    return r;
  };
  __half* buf_h  = (__half*)alloc((size_t)N * GHC * 2);
  float* xA      = (float*)alloc((size_t)N * CH * 4);
  float* xB      = (float*)alloc((size_t)N * CH * 4);
  float* s_log   = (float*)alloc((size_t)N * HD * 4);
  float* d_log   = (float*)alloc((size_t)N * HD * 4);
  int*   counts  = (int*)alloc((size_t)N * 4);
  int*   offs    = (int*)alloc((size_t)(N + 1) * 4);
  int*   fill    = (int*)alloc((size_t)N * 4);
  int*   csr     = (int*)alloc((size_t)Etot * 4);
  int*   blkS    = (int*)alloc((size_t)nb * 4);
  int*   carry   = (int*)alloc((size_t)nb * 4);
  int*   bnd     = (int*)alloc((size_t)(G + 1) * 4);
  float* g1buf   = (float*)alloc((size_t)G * 256 * 4);
  float* Wc1     = (float*)alloc(32 * 256 * 4);
  float* Wc2     = (float*)alloc(64 * 256 * 4);
  float* Wc3     = (float*)alloc(64 * 256 * 4);
  float* Psd1    = (float*)alloc(32 * 8 * 4);
  float* Psd2    = (float*)alloc(64 * 8 * 4);
  float* Psd3    = (float*)alloc(64 * 8 * 4);
  float* cb1     = (float*)alloc(64 * 4);
  float* cb2     = (float*)alloc(64 * 4);
  float* cb3     = (float*)alloc(64 * 4);

  hipMemsetAsync(counts, 0, (size_t)N * 4, stream);
  hipMemsetAsync(fill,   0, (size_t)N * 4, stream);

  count_deg<<<(Etot + 255) / 256, 256, 0, stream>>>(ei, E, N, counts);
  scan_local<<<nb, 256, 0, stream>>>(counts, N, offs, blkS);
  scan_carry<<<1, 256, 0, stream>>>(blkS, nb, carry);
  scan_add<<<nb, 256, 0, stream>>>(offs, carry, N, Etot);
  fill_csr<<<(Etot + 255) / 256, 256, 0, stream>>>(ei, E, N, offs, fill, csr);
  graph_bounds<<<(G + 256) / 256, 256, 0, stream>>>(batch, N, G, bnd);

  fuse_weights<<<33, 256, 0, stream>>>(W1, a1s, a1d, b1, h1w, h1b, 32, Wc1, Psd1, cb1);
  fuse_weights<<<65, 256, 0, stream>>>(W2, a2s, a2d, b2, h2w, h2b, 64, Wc2, Psd2, cb2);
  fuse_weights<<<65, 256, 0, stream>>>(W3, a3s, a3d, b3, h3w, h3b, 64, Wc3, Psd3, cb3);

  const int gb = (N + 15) / 16;
  const int ab = (N + 3) / 4;

  feat_gemm<32><<<gb, 256, 0, stream>>>(x, Wc1, Psd1, buf_h, s_log, d_log, N);
  gat_aggregate<true><<<ab, 256, 0, stream>>>(buf_h, s_log, d_log, offs, csr, cb1, xA, N);

  feat_gemm<64><<<gb, 256, 0, stream>>>(xA, Wc2, Psd2, buf_h, s_log, d_log, N);
  gat_aggregate<true><<<ab, 256, 0, stream>>>(buf_h, s_log, d_log, offs, csr, cb2, xB, N);

  feat_gemm<64><<<gb, 256, 0, stream>>>(xB, Wc3, Psd3, buf_h, s_log, d_log, N);
  gat_aggregate<false><<<ab, 256, 0, stream>>>(buf_h, s_log, d_log, offs, csr, cb3, xA, N);

  pool_mlp1<<<G, 256, 0, stream>>>(xA, bnd, m1w, m1b, g1buf);
  mlp2_kernel<<<G, 256, 0, stream>>>(g1buf, m2w, m2b, (float*)d_out);
}

// Round 5
// 401.346 us; speedup vs baseline: 2.6965x; 1.1324x over previous
//
#include <hip/hip_runtime.h>
#include <hip/hip_bf16.h>
#include <hip/hip_fp16.h>
#include <math.h>

#define HD 4
#define CH 64
#define GHC 256
#define NEG 0.2f

#define WAVE_SYNC() do { __builtin_amdgcn_wave_barrier(); \
                         asm volatile("s_waitcnt lgkmcnt(0)" ::: "memory"); } while (0)

__device__ __forceinline__ float wred_sum64(float v){
  #pragma unroll
  for (int o = 32; o > 0; o >>= 1) v += __shfl_xor(v, o);
  return v;
}
__device__ __forceinline__ float wred_max64(float v){
  #pragma unroll
  for (int o = 32; o > 0; o >>= 1) v = fmaxf(v, __shfl_xor(v, o));
  return v;
}

// ---------------- CSR build ----------------
__global__ __launch_bounds__(256)
void count_deg(const int* __restrict__ ei, int E, int N, int* __restrict__ cnt){
  int i = blockIdx.x * 256 + threadIdx.x;
  int tot = E + N;
  if (i >= tot) return;
  int dst = (i < E) ? ei[E + i] : (i - E);
  atomicAdd(&cnt[dst], 1);
}

__global__ __launch_bounds__(256)
void scan_local(const int* __restrict__ cnt, int N, int* __restrict__ off, int* __restrict__ blkS){
  __shared__ int sh[256];
  int tid = threadIdx.x;
  int i = blockIdx.x * 256 + tid;
  int v = (i < N) ? cnt[i] : 0;
  sh[tid] = v;
  __syncthreads();
  for (int o = 1; o < 256; o <<= 1){
    int t = (tid >= o) ? sh[tid - o] : 0;
    __syncthreads();
    sh[tid] += t;
    __syncthreads();
  }
  if (i < N) off[i] = sh[tid] - v;      // exclusive within block
  if (tid == 255) blkS[blockIdx.x] = sh[255];
}

__global__ __launch_bounds__(256)
void scan_carry(const int* __restrict__ blkS, int nb, int* __restrict__ carry){
  __shared__ int sh[256];
  int tid = threadIdx.x;
  int v = (tid < nb) ? blkS[tid] : 0;   // requires nb <= 256 (N=50000 -> nb=196)
  sh[tid] = v;
  __syncthreads();
  for (int o = 1; o < 256; o <<= 1){
    int t = (tid >= o) ? sh[tid - o] : 0;
    __syncthreads();
    sh[tid] += t;
    __syncthreads();
  }
  if (tid < nb) carry[tid] = sh[tid] - v;
}

__global__ __launch_bounds__(256)
void scan_add(int* __restrict__ off, const int* __restrict__ carry, int N, int Etot){
  int i = blockIdx.x * 256 + threadIdx.x;
  if (i < N) off[i] += carry[blockIdx.x];
  if (i == 0) off[N] = Etot;
}

__global__ __launch_bounds__(256)
void fill_csr(const int* __restrict__ ei, int E, int N, const int* __restrict__ off,
              int* __restrict__ fill, int* __restrict__ csr){
  int i = blockIdx.x * 256 + threadIdx.x;
  int tot = E + N;
  if (i >= tot) return;
  int src, dst;
  if (i < E){ src = ei[i]; dst = ei[E + i]; }
  else { src = dst = i - E; }
  int pos = off[dst] + atomicAdd(&fill[dst], 1);
  csr[pos] = src;
}

// ---------------- fused-weight precompute (per layer) ----------------
// Wcp[(h*FIN + k)*64 + c] = sum_j W[k][h*64+j] * hlw[h*64+j][c]
// Psd[k*8 + q] = sum_j W[k][h*64+j] * a[h][j]   (q<4: src head q; q>=4: dst head q-4)
// cb[c]        = hlb[c] + sum_j bl[j] * hlw[j][c]
__global__ __launch_bounds__(256)
void fuse_weights(const float* __restrict__ W, const float* __restrict__ as,
                  const float* __restrict__ ad, const float* __restrict__ bl,
                  const float* __restrict__ hlw, const float* __restrict__ hlb,
                  int FIN, float* __restrict__ Wcp, float* __restrict__ Psd,
                  float* __restrict__ cb)
{
  const int b = blockIdx.x, t = threadIdx.x;
  if (b < FIN){
    const int c = t >> 2, h = t & 3;
    const float* wrow = W + b * GHC + h * 64;
    float acc = 0.f;
    #pragma unroll 8
    for (int j = 0; j < 64; j++)
      acc += wrow[j] * hlw[(h * 64 + j) * CH + c];
    Wcp[(h * FIN + b) * CH + c] = acc;
    if (t < 8){
      const int hh = t & 3;
      const float* a = (t < 4) ? as : ad;
      const float* wr2 = W + b * GHC + hh * 64;
      float p = 0.f;
      #pragma unroll 8
      for (int j = 0; j < 64; j++) p += wr2[j] * a[hh * 64 + j];
      Psd[b * 8 + t] = p;
    }
  } else if (t < CH){
    float acc = hlb[t];
    for (int j = 0; j < GHC; j++) acc += bl[j] * hlw[j * CH + t];
    cb[t] = acc;
  }
}

// ---------------- layer-1 logits from raw x ----------------
__global__ __launch_bounds__(256)
void logits_from_x(const float* __restrict__ x, const float* __restrict__ Psd,
                   float* __restrict__ s_log, float* __restrict__ d_log, int N)
{
  int idx = blockIdx.x * 256 + threadIdx.x;
  int node = idx >> 3, q = idx & 7;
  if (node >= N) return;
  const float* xr = x + (size_t)node * 32;
  float v = 0.f;
  #pragma unroll 8
  for (int k = 0; k < 32; k++) v += xr[k] * Psd[k * 8 + q];
  if (q < 4) s_log[node * 4 + q]       = v;
  else       d_log[node * 4 + (q - 4)] = v;
}

// ---------------- aggregation: z[n,hd,k] = sum_e alpha_e^hd * x[src_e,k] ----------------
// One WAVE per destination node. F=32: x is f32 [N,32], lane=(k=lane&31, head-pair hp=lane>>5),
// z width 128. F=64: x is fp16 [N,64], lane=k, 4 head accumulators, z width 256.
template<int F>
__global__ __launch_bounds__(256)
void gat_aggregate_z(const void* __restrict__ xin, const float* __restrict__ s_log,
                     const float* __restrict__ d_log, const int* __restrict__ off,
                     const int* __restrict__ csr, __half* __restrict__ z, int N)
{
  __shared__ float4 qa[4][64];
  __shared__ int    qs[4][64];
  const int wv   = threadIdx.x >> 6;
  const int lane = threadIdx.x & 63;
  const int n = blockIdx.x * 4 + wv;
  if (n >= N) return;
  const int beg = off[n];
  const int deg = off[n + 1] - beg;

  const float4 d4v = reinterpret_cast<const float4*>(d_log)[n];
  const float d4[4] = {d4v.x, d4v.y, d4v.z, d4v.w};

  float m[4], den[4], ex[4];
  int s = 0;

  // ---- chunk 0 softmax stats ----
  {
    const bool act = lane < deg;
    float v[4];
    if (act){
      s = csr[beg + lane];
      float4 sl = reinterpret_cast<const float4*>(s_log)[s];
      float t[4] = {sl.x, sl.y, sl.z, sl.w};
      #pragma unroll
      for (int i = 0; i < 4; i++){ float u = t[i] + d4[i]; v[i] = (u >= 0.f) ? u : NEG * u; }
    } else {
      #pragma unroll
      for (int i = 0; i < 4; i++) v[i] = -INFINITY;
    }
    #pragma unroll
    for (int i = 0; i < 4; i++){
      m[i] = wred_max64(v[i]);
      ex[i] = act ? __expf(v[i] - m[i]) : 0.f;
      den[i] = wred_sum64(ex[i]);
    }
  }
  // ---- remaining chunks (rare: deg > 64), online rescale ----
  for (int base = 64; base < deg; base += 64){
    const int k = base + lane;
    const bool act = k < deg;
    float v[4];
    if (act){
      int s2 = csr[beg + k];
      float4 sl = reinterpret_cast<const float4*>(s_log)[s2];
      float t[4] = {sl.x, sl.y, sl.z, sl.w};
      #pragma unroll
      for (int i = 0; i < 4; i++){ float u = t[i] + d4[i]; v[i] = (u >= 0.f) ? u : NEG * u; }
    } else {
      #pragma unroll
      for (int i = 0; i < 4; i++) v[i] = -INFINITY;
    }
    #pragma unroll
    for (int i = 0; i < 4; i++){
      float cm = wred_max64(v[i]);
      float mn = fmaxf(m[i], cm);
      float e2 = act ? __expf(v[i] - mn) : 0.f;
      den[i] = den[i] * __expf(m[i] - mn) + wred_sum64(e2);
      m[i] = mn;
    }
  }

  float dninv[4];
  #pragma unroll
  for (int i = 0; i < 4; i++) dninv[i] = 1.f / fmaxf(den[i], 1e-16f);

  float a0 = 0.f, a1 = 0.f, a2 = 0.f, a3 = 0.f;
  const int kk = lane & 31, hp = lane >> 5;   // F=32 mapping

  auto accum = [&](int cnt){
    if (F == 64){
      const __half* xh = (const __half*)xin;
      #pragma unroll 2
      for (int e = 0; e < cnt; e++){
        float4 al = qa[wv][e];
        int src   = qs[wv][e];
        float xv  = __half2float(xh[src * 64 + lane]);
        a0 += al.x * xv; a1 += al.y * xv; a2 += al.z * xv; a3 += al.w * xv;
      }
    } else {
      const float* xf = (const float*)xin;
      #pragma unroll 2
      for (int e = 0; e < cnt; e++){
        float4 al = qa[wv][e];
        int src   = qs[wv][e];
        float xv  = xf[src * 32 + kk];
        float w0 = hp ? al.z : al.x;
        float w1 = hp ? al.w : al.y;
        a0 += w0 * xv; a1 += w1 * xv;
      }
    }
  };

  if (deg <= 64){
    qa[wv][lane] = make_float4(ex[0] * dninv[0], ex[1] * dninv[1],
                               ex[2] * dninv[2], ex[3] * dninv[3]);
    qs[wv][lane] = s;
    WAVE_SYNC();
    accum(deg);
  } else {
    for (int base = 0; base < deg; base += 64){
      const int k = base + lane;
      int s2 = 0; float al[4] = {0.f, 0.f, 0.f, 0.f};
      if (k < deg){
        s2 = csr[beg + k];
        float4 sl = reinterpret_cast<const float4*>(s_log)[s2];
        float t[4] = {sl.x, sl.y, sl.z, sl.w};
        #pragma unroll
        for (int i = 0; i < 4; i++){
          float u = t[i] + d4[i]; u = (u >= 0.f) ? u : NEG * u;
          al[i] = __expf(u - m[i]) * dninv[i];
        }
      }
      qa[wv][lane] = make_float4(al[0], al[1], al[2], al[3]);
      qs[wv][lane] = s2;
      WAVE_SYNC();
      accum(min(64, deg - base));
      WAVE_SYNC();
    }
  }

  if (F == 64){
    const size_t zb = (size_t)n * 256;
    z[zb + lane]       = __float2half(a0);
    z[zb + 64 + lane]  = __float2half(a1);
    z[zb + 128 + lane] = __float2half(a2);
    z[zb + 192 + lane] = __float2half(a3);
  } else {
    const size_t zb = (size_t)n * 128 + hp * 64 + kk;
    z[zb]      = __float2half(a0);
    z[zb + 32] = __float2half(a1);
  }
}

// ---------------- z transform: x_out[n,c] = relu(z[n,:] @ Wcp + cb), + next-layer logits ----------------
template<int ZW, bool RELU, bool LOGITS>
__global__ __launch_bounds__(256)
void z_transform(const __half* __restrict__ z, const float* __restrict__ Wcp,
                 const float* __restrict__ cb, const float* __restrict__ Psd,
                 __half* __restrict__ xo, float* __restrict__ s_log,
                 float* __restrict__ d_log, int N)
{
  const int tid = threadIdx.x;
  const int n0 = blockIdx.x * 16;
  __shared__ float zs[16][ZW];
  __shared__ float outs[16][CH];
  __shared__ float ps[CH][8];

  const __half2* zp = (const __half2*)(z + (size_t)n0 * ZW);
  const int TOT = 16 * ZW / 2;
  for (int idx = tid; idx < TOT; idx += 256){
    int node = idx / (ZW / 2);
    int jh   = idx % (ZW / 2);
    float2 f = make_float2(0.f, 0.f);
    if (n0 + node < N) f = __half22float2(zp[idx]);
    zs[node][2 * jh]     = f.x;
    zs[node][2 * jh + 1] = f.y;
  }
  if (LOGITS){
    for (int idx = tid; idx < CH * 8; idx += 256) ps[idx >> 3][idx & 7] = Psd[idx];
  }
  __syncthreads();

  const int c = tid & 63, q = tid >> 6;
  float acc[4] = {0.f, 0.f, 0.f, 0.f};
  for (int k = 0; k < ZW; k++){
    float wv = Wcp[k * CH + c];
    #pragma unroll
    for (int i = 0; i < 4; i++) acc[i] += zs[q * 4 + i][k] * wv;
  }
  const float bb = cb[c];
  #pragma unroll
  for (int i = 0; i < 4; i++){
    int node = n0 + q * 4 + i;
    if (node < N){
      float v = acc[i] + bb;
      if (RELU) v = fmaxf(v, 0.f);
      xo[(size_t)node * CH + c] = __float2half(v);
      if (LOGITS) outs[q * 4 + i][c] = v;
    }
  }
  if (LOGITS){
    __syncthreads();
    if (tid < 128){
      int nn = tid >> 3, q8 = tid & 7;
      int node = n0 + nn;
      if (node < N){
        float v = 0.f;
        #pragma unroll 8
        for (int cc = 0; cc < CH; cc++) v += outs[nn][cc] * ps[cc][q8];
        if (q8 < 4) s_log[node * 4 + q8]       = v;
        else        d_log[node * 4 + (q8 - 4)] = v;
      }
    }
  }
}

// ---------------- pooling + MLP head ----------------
__global__ __launch_bounds__(256)
void graph_bounds(const int* __restrict__ batch, int N, int G, int* __restrict__ bnd){
  int g = blockIdx.x * 256 + threadIdx.x;
  if (g > G) return;
  if (g == G){ bnd[G] = N; return; }
  int lo = 0, hi = N;
  while (lo < hi){ int mid = (lo + hi) >> 1; if (batch[mid] < g) lo = mid + 1; else hi = mid; }
  bnd[g] = lo;
}

__global__ __launch_bounds__(256)
void pool_mlp1(const __half* __restrict__ x3, const int* __restrict__ bnd,
               const float* __restrict__ w, const float* __restrict__ b,
               float* __restrict__ g1)
{
  const int g = blockIdx.x;
  const int tid = threadIdx.x;
  const int s = bnd[g], e = bnd[g + 1];
  const int c = tid & 63, j = tid >> 6;
  float acc = 0.f;
  for (int n = s + j; n < e; n += 4)
    acc += __half2float(x3[(size_t)n * CH + c]);
  __shared__ float sh[4][CH];
  __shared__ float mean[CH];
  sh[j][c] = acc;
  __syncthreads();
  if (tid < CH){
    float cnt = (float)max(e - s, 1);
    mean[tid] = (sh[0][tid] + sh[1][tid] + sh[2][tid] + sh[3][tid]) / cnt;
  }
  __syncthreads();
  float a = b[tid];
  #pragma unroll 8
  for (int cc = 0; cc < CH; cc++) a += mean[cc] * w[cc * 256 + tid];
  g1[g * 256 + tid] = fmaxf(a, 0.f);
}

__global__ __launch_bounds__(256)
void mlp2_kernel(const float* __restrict__ g1, const float* __restrict__ w,
                 const float* __restrict__ b, float* __restrict__ out)
{
  int g = blockIdx.x;
  int tid = threadIdx.x;
  __shared__ float row[256];
  row[tid] = g1[g * 256 + tid];
  __syncthreads();
  float acc = b[tid];
  for (int k = 0; k < 256; k++) acc += row[k] * w[k * 256 + tid];
  out[g * 256 + tid] = acc;
}

// ---------------- launcher ----------------
extern "C" void kernel_launch(void* const* d_in, const int* in_sizes, int n_in,
                              void* d_out, int out_size, void* d_ws, size_t ws_size,
                              hipStream_t stream)
{
  const float* x     = (const float*)d_in[0];
  const int*   ei    = (const int*)d_in[1];
  const int*   batch = (const int*)d_in[2];
  const float* W1  = (const float*)d_in[4];
  const float* a1s = (const float*)d_in[5];
  const float* a1d = (const float*)d_in[6];
  const float* b1  = (const float*)d_in[7];
  const float* h1w = (const float*)d_in[8];
  const float* h1b = (const float*)d_in[9];
  const float* W2  = (const float*)d_in[10];
  const float* a2s = (const float*)d_in[11];
  const float* a2d = (const float*)d_in[12];
  const float* b2  = (const float*)d_in[13];
  const float* h2w = (const float*)d_in[14];
  const float* h2b = (const float*)d_in[15];
  const float* W3  = (const float*)d_in[16];
  const float* a3s = (const float*)d_in[17];
  const float* a3d = (const float*)d_in[18];
  const float* b3  = (const float*)d_in[19];
  const float* h3w = (const float*)d_in[20];
  const float* h3b = (const float*)d_in[21];
  const float* m1w = (const float*)d_in[22];
  const float* m1b = (const float*)d_in[23];
  const float* m2w = (const float*)d_in[24];
  const float* m2b = (const float*)d_in[25];

  const int N = in_sizes[0] / 32;
  const int E = in_sizes[1] / 2;
  const int G = out_size / 256;
  const int Etot = E + N;
  const int nb = (N + 255) / 256;

  char* p = (char*)d_ws;
  auto alloc = [&](size_t bytes) -> void* {
    void* r = (void*)p;
    p += ((bytes + 255) / 256) * 256;
    return r;
  };
  __half* zbuf   = (__half*)alloc((size_t)N * GHC * 2);
  __half* xh1    = (__half*)alloc((size_t)N * CH * 2);
  __half* xh2    = (__half*)alloc((size_t)N * CH * 2);
  __half* xh3    = (__half*)alloc((size_t)N * CH * 2);
  float* s_log   = (float*)alloc((size_t)N * HD * 4);
  float* d_log   = (float*)alloc((size_t)N * HD * 4);
  int*   counts  = (int*)alloc((size_t)N * 4);
  int*   offs    = (int*)alloc((size_t)(N + 1) * 4);
  int*   fill    = (int*)alloc((size_t)N * 4);
  int*   csr     = (int*)alloc((size_t)Etot * 4);
  int*   blkS    = (int*)alloc((size_t)nb * 4);
  int*   carry   = (int*)alloc((size_t)nb * 4);
  int*   bnd     = (int*)alloc((size_t)(G + 1) * 4);
  float* g1buf   = (float*)alloc((size_t)G * 256 * 4);
  float* Wcp1    = (float*)alloc(128 * 64 * 4);
  float* Wcp2    = (float*)alloc(256 * 64 * 4);
  float* Wcp3    = (float*)alloc(256 * 64 * 4);
  float* Psd1    = (float*)alloc(32 * 8 * 4);
  float* Psd2    = (float*)alloc(64 * 8 * 4);
  float* Psd3    = (float*)alloc(64 * 8 * 4);
  float* cb1     = (float*)alloc(64 * 4);
  float* cb2     = (float*)alloc(64 * 4);
  float* cb3     = (float*)alloc(64 * 4);

  hipMemsetAsync(counts, 0, (size_t)N * 4, stream);
  hipMemsetAsync(fill,   0, (size_t)N * 4, stream);

  count_deg<<<(Etot + 255) / 256, 256, 0, stream>>>(ei, E, N, counts);
  scan_local<<<nb, 256, 0, stream>>>(counts, N, offs, blkS);
  scan_carry<<<1, 256, 0, stream>>>(blkS, nb, carry);
  scan_add<<<nb, 256, 0, stream>>>(offs, carry, N, Etot);
  fill_csr<<<(Etot + 255) / 256, 256, 0, stream>>>(ei, E, N, offs, fill, csr);
  graph_bounds<<<(G + 256) / 256, 256, 0, stream>>>(batch, N, G, bnd);

  fuse_weights<<<33, 256, 0, stream>>>(W1, a1s, a1d, b1, h1w, h1b, 32, Wcp1, Psd1, cb1);
  fuse_weights<<<65, 256, 0, stream>>>(W2, a2s, a2d, b2, h2w, h2b, 64, Wcp2, Psd2, cb2);
  fuse_weights<<<65, 256, 0, stream>>>(W3, a3s, a3d, b3, h3w, h3b, 64, Wcp3, Psd3, cb3);

  const int gb = (N + 15) / 16;
  const int ab = (N + 3) / 4;

  logits_from_x<<<((size_t)N * 8 + 255) / 256, 256, 0, stream>>>(x, Psd1, s_log, d_log, N);

  gat_aggregate_z<32><<<ab, 256, 0, stream>>>(x, s_log, d_log, offs, csr, zbuf, N);
  z_transform<128, true, true><<<gb, 256, 0, stream>>>(zbuf, Wcp1, cb1, Psd2, xh1, s_log, d_log, N);

  gat_aggregate_z<64><<<ab, 256, 0, stream>>>(xh1, s_log, d_log, offs, csr, zbuf, N);
  z_transform<256, true, true><<<gb, 256, 0, stream>>>(zbuf, Wcp2, cb2, Psd3, xh2, s_log, d_log, N);

  gat_aggregate_z<64><<<ab, 256, 0, stream>>>(xh2, s_log, d_log, offs, csr, zbuf, N);
  z_transform<256, false, false><<<gb, 256, 0, stream>>>(zbuf, Wcp3, cb3, nullptr, xh3, nullptr, nullptr, N);

  pool_mlp1<<<G, 256, 0, stream>>>(xh3, bnd, m1w, m1b, g1buf);
  mlp2_kernel<<<G, 256, 0, stream>>>(g1buf, m2w, m2b, (float*)d_out);
}

// Round 6
// 339.461 us; speedup vs baseline: 3.1880x; 1.1823x over previous
//
#include <hip/hip_runtime.h>
#include <hip/hip_bf16.h>
#include <hip/hip_fp16.h>
#include <math.h>

#define HD 4
#define CH 64
#define GHC 256
#define NEG 0.2f

#define WAVE_SYNC() do { __builtin_amdgcn_wave_barrier(); \
                         asm volatile("s_waitcnt lgkmcnt(0)" ::: "memory"); } while (0)

typedef _Float16 f16x8 __attribute__((ext_vector_type(8)));
typedef float f32x4 __attribute__((ext_vector_type(4)));

__device__ __forceinline__ float wred_sum64(float v){
  #pragma unroll
  for (int o = 32; o > 0; o >>= 1) v += __shfl_xor(v, o);
  return v;
}
__device__ __forceinline__ float wred_max64(float v){
  #pragma unroll
  for (int o = 32; o > 0; o >>= 1) v = fmaxf(v, __shfl_xor(v, o));
  return v;
}

// ---------------- CSR build ----------------
__global__ __launch_bounds__(256)
void count_deg(const int* __restrict__ ei, int E, int N, int* __restrict__ cnt){
  int i = blockIdx.x * 256 + threadIdx.x;
  int tot = E + N;
  if (i >= tot) return;
  int dst = (i < E) ? ei[E + i] : (i - E);
  atomicAdd(&cnt[dst], 1);
}

__global__ __launch_bounds__(256)
void scan_local(const int* __restrict__ cnt, int N, int* __restrict__ off, int* __restrict__ blkS){
  __shared__ int sh[256];
  int tid = threadIdx.x;
  int i = blockIdx.x * 256 + tid;
  int v = (i < N) ? cnt[i] : 0;
  sh[tid] = v;
  __syncthreads();
  for (int o = 1; o < 256; o <<= 1){
    int t = (tid >= o) ? sh[tid - o] : 0;
    __syncthreads();
    sh[tid] += t;
    __syncthreads();
  }
  if (i < N) off[i] = sh[tid] - v;      // exclusive within block
  if (tid == 255) blkS[blockIdx.x] = sh[255];
}

__global__ __launch_bounds__(256)
void scan_carry(const int* __restrict__ blkS, int nb, int* __restrict__ carry){
  __shared__ int sh[256];
  int tid = threadIdx.x;
  int v = (tid < nb) ? blkS[tid] : 0;   // requires nb <= 256 (N=50000 -> nb=196)
  sh[tid] = v;
  __syncthreads();
  for (int o = 1; o < 256; o <<= 1){
    int t = (tid >= o) ? sh[tid - o] : 0;
    __syncthreads();
    sh[tid] += t;
    __syncthreads();
  }
  if (tid < nb) carry[tid] = sh[tid] - v;
}

__global__ __launch_bounds__(256)
void scan_add(int* __restrict__ off, const int* __restrict__ carry, int N, int Etot){
  int i = blockIdx.x * 256 + threadIdx.x;
  if (i < N) off[i] += carry[blockIdx.x];
  if (i == 0) off[N] = Etot;
}

__global__ __launch_bounds__(256)
void fill_csr(const int* __restrict__ ei, int E, int N, const int* __restrict__ off,
              int* __restrict__ fill, int* __restrict__ csr){
  int i = blockIdx.x * 256 + threadIdx.x;
  int tot = E + N;
  if (i >= tot) return;
  int src, dst;
  if (i < E){ src = ei[i]; dst = ei[E + i]; }
  else { src = dst = i - E; }
  int pos = off[dst] + atomicAdd(&fill[dst], 1);
  csr[pos] = src;
}

// ---------------- fused-weight precompute (per layer) ----------------
// Wcp[(h*FIN + k)*64 + c] = sum_j W[k][h*64+j] * hlw[h*64+j][c]
// Psd[k*8 + q] = sum_j W[k][h*64+j] * a[h][j]   (q<4: src head q; q>=4: dst head q-4)
// cb[c]        = hlb[c] + sum_j bl[j] * hlw[j][c]
__global__ __launch_bounds__(256)
void fuse_weights(const float* __restrict__ W, const float* __restrict__ as,
                  const float* __restrict__ ad, const float* __restrict__ bl,
                  const float* __restrict__ hlw, const float* __restrict__ hlb,
                  int FIN, float* __restrict__ Wcp, float* __restrict__ Psd,
                  float* __restrict__ cb)
{
  const int b = blockIdx.x, t = threadIdx.x;
  if (b < FIN){
    const int c = t >> 2, h = t & 3;
    const float* wrow = W + b * GHC + h * 64;
    float acc = 0.f;
    #pragma unroll 8
    for (int j = 0; j < 64; j++)
      acc += wrow[j] * hlw[(h * 64 + j) * CH + c];
    Wcp[(h * FIN + b) * CH + c] = acc;
    if (t < 8){
      const int hh = t & 3;
      const float* a = (t < 4) ? as : ad;
      const float* wr2 = W + b * GHC + hh * 64;
      float p = 0.f;
      #pragma unroll 8
      for (int j = 0; j < 64; j++) p += wr2[j] * a[hh * 64 + j];
      Psd[b * 8 + t] = p;
    }
  } else if (t < CH){
    float acc = hlb[t];
    for (int j = 0; j < GHC; j++) acc += bl[j] * hlw[j * CH + t];
    cb[t] = acc;
  }
}

// ---------------- pack fp16 MFMA B-fragments ----------------
// Wpk element idx = ((ks*4+nt)*64 + lane)*8 + j  <-  Wcp[k*64+c], k=ks*32+(lane>>4)*8+j, c=nt*16+(lane&15)
// Ppk element idx = (ks*64 + lane)*8 + j         <-  Psd[k*8+col] if col<8 else 0, col=lane&15
__global__ __launch_bounds__(256)
void pack_all(const float* __restrict__ Wcp1, const float* __restrict__ Wcp2,
              const float* __restrict__ Psd2, const float* __restrict__ Psd3,
              __half* __restrict__ Wpk1, __half* __restrict__ Wpk2,
              __half* __restrict__ Ppk2, __half* __restrict__ Ppk3)
{
  int idx = blockIdx.x * 256 + threadIdx.x;
  if (idx < 8192){
    int t = idx;
    int j = t & 7, lane = (t >> 3) & 63, fr = t >> 9;
    int k = (fr >> 2) * 32 + (lane >> 4) * 8 + j;
    int c = (fr & 3) * 16 + (lane & 15);
    Wpk1[t] = __float2half(Wcp1[k * 64 + c]);
  } else if (idx < 24576){
    int t = idx - 8192;
    int j = t & 7, lane = (t >> 3) & 63, fr = t >> 9;
    int k = (fr >> 2) * 32 + (lane >> 4) * 8 + j;
    int c = (fr & 3) * 16 + (lane & 15);
    Wpk2[t] = __float2half(Wcp2[k * 64 + c]);
  } else if (idx < 25600){
    int t = idx - 24576;
    int j = t & 7, lane = (t >> 3) & 63, ks = t >> 9;
    int k = ks * 32 + (lane >> 4) * 8 + j;
    int col = lane & 15;
    Ppk2[t] = (col < 8) ? __float2half(Psd2[k * 8 + col]) : __float2half(0.f);
  } else if (idx < 26624){
    int t = idx - 25600;
    int j = t & 7, lane = (t >> 3) & 63, ks = t >> 9;
    int k = ks * 32 + (lane >> 4) * 8 + j;
    int col = lane & 15;
    Ppk3[t] = (col < 8) ? __float2half(Psd3[k * 8 + col]) : __float2half(0.f);
  }
}

// ---------------- layer-1 logits from raw x ----------------
__global__ __launch_bounds__(256)
void logits_from_x(const float* __restrict__ x, const float* __restrict__ Psd,
                   float* __restrict__ s_log, float* __restrict__ d_log, int N)
{
  int idx = blockIdx.x * 256 + threadIdx.x;
  int node = idx >> 3, q = idx & 7;
  if (node >= N) return;
  const float* xr = x + (size_t)node * 32;
  float v = 0.f;
  #pragma unroll 8
  for (int k = 0; k < 32; k++) v += xr[k] * Psd[k * 8 + q];
  if (q < 4) s_log[node * 4 + q]       = v;
  else       d_log[node * 4 + (q - 4)] = v;
}

// ---------------- aggregation: z[n,hd,k] = sum_e alpha_e^hd * x[src_e,k] ----------------
template<int F>
__global__ __launch_bounds__(256)
void gat_aggregate_z(const void* __restrict__ xin, const float* __restrict__ s_log,
                     const float* __restrict__ d_log, const int* __restrict__ off,
                     const int* __restrict__ csr, __half* __restrict__ z, int N)
{
  __shared__ float4 qa[4][64];
  __shared__ int    qs[4][64];
  const int wv   = threadIdx.x >> 6;
  const int lane = threadIdx.x & 63;
  const int n = blockIdx.x * 4 + wv;
  if (n >= N) return;
  const int beg = off[n];
  const int deg = off[n + 1] - beg;

  const float4 d4v = reinterpret_cast<const float4*>(d_log)[n];
  const float d4[4] = {d4v.x, d4v.y, d4v.z, d4v.w};

  float m[4], den[4], ex[4];
  int s = 0;

  // ---- chunk 0 softmax stats ----
  {
    const bool act = lane < deg;
    float v[4];
    if (act){
      s = csr[beg + lane];
      float4 sl = reinterpret_cast<const float4*>(s_log)[s];
      float t[4] = {sl.x, sl.y, sl.z, sl.w};
      #pragma unroll
      for (int i = 0; i < 4; i++){ float u = t[i] + d4[i]; v[i] = (u >= 0.f) ? u : NEG * u; }
    } else {
      #pragma unroll
      for (int i = 0; i < 4; i++) v[i] = -INFINITY;
    }
    #pragma unroll
    for (int i = 0; i < 4; i++){
      m[i] = wred_max64(v[i]);
      ex[i] = act ? __expf(v[i] - m[i]) : 0.f;
      den[i] = wred_sum64(ex[i]);
    }
  }
  // ---- remaining chunks (rare: deg > 64), online rescale ----
  for (int base = 64; base < deg; base += 64){
    const int k = base + lane;
    const bool act = k < deg;
    float v[4];
    if (act){
      int s2 = csr[beg + k];
      float4 sl = reinterpret_cast<const float4*>(s_log)[s2];
      float t[4] = {sl.x, sl.y, sl.z, sl.w};
      #pragma unroll
      for (int i = 0; i < 4; i++){ float u = t[i] + d4[i]; v[i] = (u >= 0.f) ? u : NEG * u; }
    } else {
      #pragma unroll
      for (int i = 0; i < 4; i++) v[i] = -INFINITY;
    }
    #pragma unroll
    for (int i = 0; i < 4; i++){
      float cm = wred_max64(v[i]);
      float mn = fmaxf(m[i], cm);
      float e2 = act ? __expf(v[i] - mn) : 0.f;
      den[i] = den[i] * __expf(m[i] - mn) + wred_sum64(e2);
      m[i] = mn;
    }
  }

  float dninv[4];
  #pragma unroll
  for (int i = 0; i < 4; i++) dninv[i] = 1.f / fmaxf(den[i], 1e-16f);

  float a0 = 0.f, a1 = 0.f, a2 = 0.f, a3 = 0.f;
  const int kk = lane & 31, hp = lane >> 5;   // F=32 mapping

  auto accum = [&](int cnt){
    if (F == 64){
      const __half* xh = (const __half*)xin;
      #pragma unroll 2
      for (int e = 0; e < cnt; e++){
        float4 al = qa[wv][e];
        int src   = qs[wv][e];
        float xv  = __half2float(xh[src * 64 + lane]);
        a0 += al.x * xv; a1 += al.y * xv; a2 += al.z * xv; a3 += al.w * xv;
      }
    } else {
      const float* xf = (const float*)xin;
      #pragma unroll 2
      for (int e = 0; e < cnt; e++){
        float4 al = qa[wv][e];
        int src   = qs[wv][e];
        float xv  = xf[src * 32 + kk];
        float w0 = hp ? al.z : al.x;
        float w1 = hp ? al.w : al.y;
        a0 += w0 * xv; a1 += w1 * xv;
      }
    }
  };

  if (deg <= 64){
    qa[wv][lane] = make_float4(ex[0] * dninv[0], ex[1] * dninv[1],
                               ex[2] * dninv[2], ex[3] * dninv[3]);
    qs[wv][lane] = s;
    WAVE_SYNC();
    accum(deg);
  } else {
    for (int base = 0; base < deg; base += 64){
      const int k = base + lane;
      int s2 = 0; float al[4] = {0.f, 0.f, 0.f, 0.f};
      if (k < deg){
        s2 = csr[beg + k];
        float4 sl = reinterpret_cast<const float4*>(s_log)[s2];
        float t[4] = {sl.x, sl.y, sl.z, sl.w};
        #pragma unroll
        for (int i = 0; i < 4; i++){
          float u = t[i] + d4[i]; u = (u >= 0.f) ? u : NEG * u;
          al[i] = __expf(u - m[i]) * dninv[i];
        }
      }
      qa[wv][lane] = make_float4(al[0], al[1], al[2], al[3]);
      qs[wv][lane] = s2;
      WAVE_SYNC();
      accum(min(64, deg - base));
      WAVE_SYNC();
    }
  }

  if (F == 64){
    const size_t zb = (size_t)n * 256;
    z[zb + lane]       = __float2half(a0);
    z[zb + 64 + lane]  = __float2half(a1);
    z[zb + 128 + lane] = __float2half(a2);
    z[zb + 192 + lane] = __float2half(a3);
  } else {
    const size_t zb = (size_t)n * 128 + hp * 64 + kk;
    z[zb]      = __float2half(a0);
    z[zb + 32] = __float2half(a1);
  }
}

// ---------------- z transform via MFMA ----------------
// x_out[n,c] = relu(z[n,:] @ Wcp + cb)  (fp16 out), plus next-layer logits via MFMA vs packed Psd.
// Wave = 16 nodes. A-frag: row=lane&15, k=(lane>>4)*8+j (contiguous 16B from z row).
// C/D: col=lane&15, row=(lane>>4)*4+reg  [m89/m91-verified layout].
template<int ZW>
__global__ __launch_bounds__(256)
void z_transform_mfma(const __half* __restrict__ z, const __half* __restrict__ Wpk,
                      const float* __restrict__ cb, const __half* __restrict__ Ppk,
                      __half* __restrict__ xo, float* __restrict__ s_log,
                      float* __restrict__ d_log, int N)
{
  __shared__ float outs[4][16][68];   // +4 pad -> 2-way banks on strided reads
  __shared__ float cbs[64];
  const int tid = threadIdx.x;
  const int wv = tid >> 6, lane = tid & 63;
  const int row = lane & 15, kg = lane >> 4;
  const int n0 = blockIdx.x * 64 + wv * 16;
  if (tid < 64) cbs[tid] = cb[tid];
  __syncthreads();

  f32x4 acc0 = {0.f,0.f,0.f,0.f}, acc1 = {0.f,0.f,0.f,0.f};
  f32x4 acc2 = {0.f,0.f,0.f,0.f}, acc3 = {0.f,0.f,0.f,0.f};
  const __half* za = z + (size_t)(n0 + row) * ZW + kg * 8;
  const f16x8* wp = reinterpret_cast<const f16x8*>(Wpk) + lane;
  #pragma unroll
  for (int ks = 0; ks < ZW / 32; ks++){
    f16x8 af = *reinterpret_cast<const f16x8*>(za + ks * 32);
    acc0 = __builtin_amdgcn_mfma_f32_16x16x32_f16(af, wp[(ks*4+0)*64], acc0, 0,0,0);
    acc1 = __builtin_amdgcn_mfma_f32_16x16x32_f16(af, wp[(ks*4+1)*64], acc1, 0,0,0);
    acc2 = __builtin_amdgcn_mfma_f32_16x16x32_f16(af, wp[(ks*4+2)*64], acc2, 0,0,0);
    acc3 = __builtin_amdgcn_mfma_f32_16x16x32_f16(af, wp[(ks*4+3)*64], acc3, 0,0,0);
  }
  #pragma unroll
  for (int r = 0; r < 4; r++){
    int rr = kg * 4 + r;
    outs[wv][rr][ 0 + row] = fmaxf(acc0[r] + cbs[ 0 + row], 0.f);
    outs[wv][rr][16 + row] = fmaxf(acc1[r] + cbs[16 + row], 0.f);
    outs[wv][rr][32 + row] = fmaxf(acc2[r] + cbs[32 + row], 0.f);
    outs[wv][rr][48 + row] = fmaxf(acc3[r] + cbs[48 + row], 0.f);
  }
  WAVE_SYNC();

  // xo (fp16) coalesced-ish write: 4 x uint2 (4 halves) per lane
  #pragma unroll
  for (int i = 0; i < 4; i++){
    int idx = lane + 64 * i;
    int nn = idx >> 4, part = idx & 15;
    int node = n0 + nn;
    if (node < N){
      const float* o = &outs[wv][nn][part * 4];
      __half2 h0 = __floats2half2_rn(o[0], o[1]);
      __half2 h1 = __floats2half2_rn(o[2], o[3]);
      uint2 u;
      u.x = *reinterpret_cast<const unsigned*>(&h0);
      u.y = *reinterpret_cast<const unsigned*>(&h1);
      *reinterpret_cast<uint2*>(xo + (size_t)node * 64 + part * 4) = u;
    }
  }

  // next-layer logits: [16 x 64] @ Ppk (cols 0-7 = s/d heads)
  f32x4 lacc = {0.f,0.f,0.f,0.f};
  const f16x8* pp = reinterpret_cast<const f16x8*>(Ppk) + lane;
  #pragma unroll
  for (int ks = 0; ks < 2; ks++){
    f16x8 af;
    #pragma unroll
    for (int j = 0; j < 8; j++) af[j] = (_Float16)outs[wv][row][ks * 32 + kg * 8 + j];
    lacc = __builtin_amdgcn_mfma_f32_16x16x32_f16(af, pp[ks * 64], lacc, 0,0,0);
  }
  if (row < 8){
    float* dst = (row < 4) ? s_log : d_log;
    int q = row & 3;
    #pragma unroll
    for (int r = 0; r < 4; r++){
      int node = n0 + kg * 4 + r;
      if (node < N) dst[node * 4 + q] = lacc[r];
    }
  }
}

// ---------------- pooling + fused layer-3 projection + MLP1 ----------------
__global__ __launch_bounds__(256)
void graph_bounds(const int* __restrict__ batch, int N, int G, int* __restrict__ bnd){
  int g = blockIdx.x * 256 + threadIdx.x;
  if (g > G) return;
  if (g == G){ bnd[G] = N; return; }
  int lo = 0, hi = N;
  while (lo < hi){ int mid = (lo + hi) >> 1; if (batch[mid] < g) lo = mid + 1; else hi = mid; }
  bnd[g] = lo;
}

// mean(z3)@Wcp3 + cb3 -> t[64]; g1 = relu(t@m1w + m1b)   (layer-3 head linear has no relu,
// and mean-pool is linear, so projecting the pooled z is exact)
__global__ __launch_bounds__(256)
void pool_mlp1(const __half* __restrict__ z3, const int* __restrict__ bnd,
               const float* __restrict__ Wcp3, const float* __restrict__ cb3,
               const float* __restrict__ m1w, const float* __restrict__ m1b,
               float* __restrict__ g1)
{
  const int g = blockIdx.x, tid = threadIdx.x;
  const int s = bnd[g], e = bnd[g + 1];
  float s0 = 0.f, s1 = 0.f;
  int n = s;
  for (; n + 1 < e; n += 2){
    s0 += __half2float(z3[(size_t)n * 256 + tid]);
    s1 += __half2float(z3[(size_t)(n + 1) * 256 + tid]);
  }
  if (n < e) s0 += __half2float(z3[(size_t)n * 256 + tid]);
  __shared__ float zbar[256];
  zbar[tid] = (s0 + s1) / (float)max(e - s, 1);
  __syncthreads();
  const int c = tid & 63, part = tid >> 6;
  float tp = 0.f;
  #pragma unroll 8
  for (int k = part * 64; k < part * 64 + 64; k++) tp += zbar[k] * Wcp3[k * 64 + c];
  __shared__ float tsh[4][64];
  tsh[part][c] = tp;
  __syncthreads();
  __shared__ float tvec[64];
  if (tid < 64)
    tvec[tid] = tsh[0][tid] + tsh[1][tid] + tsh[2][tid] + tsh[3][tid] + cb3[tid];
  __syncthreads();
  float a = m1b[tid];
  #pragma unroll 8
  for (int cc = 0; cc < 64; cc++) a += tvec[cc] * m1w[cc * 256 + tid];
  g1[g * 256 + tid] = fmaxf(a, 0.f);
}

__global__ __launch_bounds__(256)
void mlp2_kernel(const float* __restrict__ g1, const float* __restrict__ w,
                 const float* __restrict__ b, float* __restrict__ out)
{
  int g = blockIdx.x;
  int tid = threadIdx.x;
  __shared__ float row[256];
  row[tid] = g1[g * 256 + tid];
  __syncthreads();
  float acc = b[tid];
  for (int k = 0; k < 256; k++) acc += row[k] * w[k * 256 + tid];
  out[g * 256 + tid] = acc;
}

// ---------------- launcher ----------------
extern "C" void kernel_launch(void* const* d_in, const int* in_sizes, int n_in,
                              void* d_out, int out_size, void* d_ws, size_t ws_size,
                              hipStream_t stream)
{
  const float* x     = (const float*)d_in[0];
  const int*   ei    = (const int*)d_in[1];
  const int*   batch = (const int*)d_in[2];
  const float* W1  = (const float*)d_in[4];
  const float* a1s = (const float*)d_in[5];
  const float* a1d = (const float*)d_in[6];
  const float* b1  = (const float*)d_in[7];
  const float* h1w = (const float*)d_in[8];
  const float* h1b = (const float*)d_in[9];
  const float* W2  = (const float*)d_in[10];
  const float* a2s = (const float*)d_in[11];
  const float* a2d = (const float*)d_in[12];
  const float* b2  = (const float*)d_in[13];
  const float* h2w = (const float*)d_in[14];
  const float* h2b = (const float*)d_in[15];
  const float* W3  = (const float*)d_in[16];
  const float* a3s = (const float*)d_in[17];
  const float* a3d = (const float*)d_in[18];
  const float* b3  = (const float*)d_in[19];
  const float* h3w = (const float*)d_in[20];
  const float* h3b = (const float*)d_in[21];
  const float* m1w = (const float*)d_in[22];
  const float* m1b = (const float*)d_in[23];
  const float* m2w = (const float*)d_in[24];
  const float* m2b = (const float*)d_in[25];

  const int N = in_sizes[0] / 32;
  const int E = in_sizes[1] / 2;
  const int G = out_size / 256;
  const int Etot = E + N;
  const int nb = (N + 255) / 256;

  char* p = (char*)d_ws;
  auto alloc = [&](size_t bytes) -> void* {
    void* r = (void*)p;
    p += ((bytes + 255) / 256) * 256;
    return r;
  };
  __half* zbuf   = (__half*)alloc((size_t)N * GHC * 2);
  __half* xh1    = (__half*)alloc((size_t)N * CH * 2);
  __half* xh2    = (__half*)alloc((size_t)N * CH * 2);
  float* s_log   = (float*)alloc((size_t)N * HD * 4);
  float* d_log   = (float*)alloc((size_t)N * HD * 4);
  int*   counts  = (int*)alloc((size_t)N * 4);
  int*   offs    = (int*)alloc((size_t)(N + 1) * 4);
  int*   fill    = (int*)alloc((size_t)N * 4);
  int*   csr     = (int*)alloc((size_t)Etot * 4);
  int*   blkS    = (int*)alloc((size_t)nb * 4);
  int*   carry   = (int*)alloc((size_t)nb * 4);
  int*   bnd     = (int*)alloc((size_t)(G + 1) * 4);
  float* g1buf   = (float*)alloc((size_t)G * 256 * 4);
  float* Wcp1    = (float*)alloc(128 * 64 * 4);
  float* Wcp2    = (float*)alloc(256 * 64 * 4);
  float* Wcp3    = (float*)alloc(256 * 64 * 4);
  float* Psd1    = (float*)alloc(32 * 8 * 4);
  float* Psd2    = (float*)alloc(64 * 8 * 4);
  float* Psd3    = (float*)alloc(64 * 8 * 4);
  float* cb1     = (float*)alloc(64 * 4);
  float* cb2     = (float*)alloc(64 * 4);
  float* cb3     = (float*)alloc(64 * 4);
  __half* Wpk1   = (__half*)alloc(128 * 64 * 2);
  __half* Wpk2   = (__half*)alloc(256 * 64 * 2);
  __half* Ppk2   = (__half*)alloc(1024 * 2);
  __half* Ppk3   = (__half*)alloc(1024 * 2);

  hipMemsetAsync(counts, 0, (size_t)N * 4, stream);
  hipMemsetAsync(fill,   0, (size_t)N * 4, stream);

  count_deg<<<(Etot + 255) / 256, 256, 0, stream>>>(ei, E, N, counts);
  scan_local<<<nb, 256, 0, stream>>>(counts, N, offs, blkS);
  scan_carry<<<1, 256, 0, stream>>>(blkS, nb, carry);
  scan_add<<<nb, 256, 0, stream>>>(offs, carry, N, Etot);
  fill_csr<<<(Etot + 255) / 256, 256, 0, stream>>>(ei, E, N, offs, fill, csr);
  graph_bounds<<<(G + 256) / 256, 256, 0, stream>>>(batch, N, G, bnd);

  fuse_weights<<<33, 256, 0, stream>>>(W1, a1s, a1d, b1, h1w, h1b, 32, Wcp1, Psd1, cb1);
  fuse_weights<<<65, 256, 0, stream>>>(W2, a2s, a2d, b2, h2w, h2b, 64, Wcp2, Psd2, cb2);
  fuse_weights<<<65, 256, 0, stream>>>(W3, a3s, a3d, b3, h3w, h3b, 64, Wcp3, Psd3, cb3);
  pack_all<<<104, 256, 0, stream>>>(Wcp1, Wcp2, Psd2, Psd3, Wpk1, Wpk2, Ppk2, Ppk3);

  const int ab = (N + 3) / 4;
  const int zb = (N + 63) / 64;

  logits_from_x<<<((size_t)N * 8 + 255) / 256, 256, 0, stream>>>(x, Psd1, s_log, d_log, N);

  gat_aggregate_z<32><<<ab, 256, 0, stream>>>(x, s_log, d_log, offs, csr, zbuf, N);
  z_transform_mfma<128><<<zb, 256, 0, stream>>>(zbuf, Wpk1, cb1, Ppk2, xh1, s_log, d_log, N);

  gat_aggregate_z<64><<<ab, 256, 0, stream>>>(xh1, s_log, d_log, offs, csr, zbuf, N);
  z_transform_mfma<256><<<zb, 256, 0, stream>>>(zbuf, Wpk2, cb2, Ppk3, xh2, s_log, d_log, N);

  gat_aggregate_z<64><<<ab, 256, 0, stream>>>(xh2, s_log, d_log, offs, csr, zbuf, N);

  pool_mlp1<<<G, 256, 0, stream>>>(zbuf, bnd, Wcp3, cb3, m1w, m1b, g1buf);
  mlp2_kernel<<<G, 256, 0, stream>>>(g1buf, m2w, m2b, (float*)d_out);
}

// Round 7
// 310.112 us; speedup vs baseline: 3.4898x; 1.0946x over previous
//
#include <hip/hip_runtime.h>
#include <hip/hip_bf16.h>
#include <hip/hip_fp16.h>
#include <math.h>

#define HD 4
#define CH 64
#define GHC 256
#define NEG 0.2f

#define WAVE_SYNC() do { __builtin_amdgcn_wave_barrier(); \
                         asm volatile("s_waitcnt lgkmcnt(0)" ::: "memory"); } while (0)

typedef _Float16 f16x8 __attribute__((ext_vector_type(8)));
typedef float f32x4 __attribute__((ext_vector_type(4)));

__device__ __forceinline__ float wred_sum64(float v){
  #pragma unroll
  for (int o = 32; o > 0; o >>= 1) v += __shfl_xor(v, o);
  return v;
}
__device__ __forceinline__ float wred_max64(float v){
  #pragma unroll
  for (int o = 32; o > 0; o >>= 1) v = fmaxf(v, __shfl_xor(v, o));
  return v;
}

// ---------------- CSR build ----------------
__global__ __launch_bounds__(256)
void count_deg(const int* __restrict__ ei, int E, int N, int* __restrict__ cnt){
  int i = blockIdx.x * 256 + threadIdx.x;
  int tot = E + N;
  if (i >= tot) return;
  int dst = (i < E) ? ei[E + i] : (i - E);
  atomicAdd(&cnt[dst], 1);
}

__global__ __launch_bounds__(256)
void scan_local(const int* __restrict__ cnt, int N, int* __restrict__ off, int* __restrict__ blkS){
  __shared__ int sh[256];
  int tid = threadIdx.x;
  int i = blockIdx.x * 256 + tid;
  int v = (i < N) ? cnt[i] : 0;
  sh[tid] = v;
  __syncthreads();
  for (int o = 1; o < 256; o <<= 1){
    int t = (tid >= o) ? sh[tid - o] : 0;
    __syncthreads();
    sh[tid] += t;
    __syncthreads();
  }
  if (i < N) off[i] = sh[tid] - v;      // exclusive within block
  if (tid == 255) blkS[blockIdx.x] = sh[255];
}

__global__ __launch_bounds__(256)
void scan_carry(const int* __restrict__ blkS, int nb, int* __restrict__ carry){
  __shared__ int sh[256];
  int tid = threadIdx.x;
  int v = (tid < nb) ? blkS[tid] : 0;   // requires nb <= 256 (N=50000 -> nb=196)
  sh[tid] = v;
  __syncthreads();
  for (int o = 1; o < 256; o <<= 1){
    int t = (tid >= o) ? sh[tid - o] : 0;
    __syncthreads();
    sh[tid] += t;
    __syncthreads();
  }
  if (tid < nb) carry[tid] = sh[tid] - v;
}

__global__ __launch_bounds__(256)
void scan_add(int* __restrict__ off, const int* __restrict__ carry, int N, int Etot){
  int i = blockIdx.x * 256 + threadIdx.x;
  if (i < N) off[i] += carry[blockIdx.x];
  if (i == 0) off[N] = Etot;
}

__global__ __launch_bounds__(256)
void fill_csr(const int* __restrict__ ei, int E, int N, const int* __restrict__ off,
              int* __restrict__ fill, unsigned short* __restrict__ csr){
  int i = blockIdx.x * 256 + threadIdx.x;
  int tot = E + N;
  if (i >= tot) return;
  int src, dst;
  if (i < E){ src = ei[i]; dst = ei[E + i]; }
  else { src = dst = i - E; }
  int pos = off[dst] + atomicAdd(&fill[dst], 1);
  csr[pos] = (unsigned short)src;
}

// ---------------- fused-weight precompute (per layer) ----------------
// Wcp[(h*FIN + k)*64 + c] = sum_j W[k][h*64+j] * hlw[h*64+j][c]
// Psd[k*8 + q] = sum_j W[k][h*64+j] * a[h][j]   (q<4: src head q; q>=4: dst head q-4)
// cb[c]        = hlb[c] + sum_j bl[j] * hlw[j][c]
__global__ __launch_bounds__(256)
void fuse_weights(const float* __restrict__ W, const float* __restrict__ as,
                  const float* __restrict__ ad, const float* __restrict__ bl,
                  const float* __restrict__ hlw, const float* __restrict__ hlb,
                  int FIN, float* __restrict__ Wcp, float* __restrict__ Psd,
                  float* __restrict__ cb)
{
  const int b = blockIdx.x, t = threadIdx.x;
  if (b < FIN){
    const int c = t >> 2, h = t & 3;
    const float* wrow = W + b * GHC + h * 64;
    float acc = 0.f;
    #pragma unroll 8
    for (int j = 0; j < 64; j++)
      acc += wrow[j] * hlw[(h * 64 + j) * CH + c];
    Wcp[(h * FIN + b) * CH + c] = acc;
    if (t < 8){
      const int hh = t & 3;
      const float* a = (t < 4) ? as : ad;
      const float* wr2 = W + b * GHC + hh * 64;
      float p = 0.f;
      #pragma unroll 8
      for (int j = 0; j < 64; j++) p += wr2[j] * a[hh * 64 + j];
      Psd[b * 8 + t] = p;
    }
  } else if (t < CH){
    float acc = hlb[t];
    for (int j = 0; j < GHC; j++) acc += bl[j] * hlw[j * CH + t];
    cb[t] = acc;
  }
}

// ---------------- pack fp16 MFMA B-fragments ----------------
__global__ __launch_bounds__(256)
void pack_all(const float* __restrict__ Wcp1, const float* __restrict__ Wcp2,
              const float* __restrict__ Psd2, const float* __restrict__ Psd3,
              __half* __restrict__ Wpk1, __half* __restrict__ Wpk2,
              __half* __restrict__ Ppk2, __half* __restrict__ Ppk3)
{
  int idx = blockIdx.x * 256 + threadIdx.x;
  if (idx < 8192){
    int t = idx;
    int j = t & 7, lane = (t >> 3) & 63, fr = t >> 9;
    int k = (fr >> 2) * 32 + (lane >> 4) * 8 + j;
    int c = (fr & 3) * 16 + (lane & 15);
    Wpk1[t] = __float2half(Wcp1[k * 64 + c]);
  } else if (idx < 24576){
    int t = idx - 8192;
    int j = t & 7, lane = (t >> 3) & 63, fr = t >> 9;
    int k = (fr >> 2) * 32 + (lane >> 4) * 8 + j;
    int c = (fr & 3) * 16 + (lane & 15);
    Wpk2[t] = __float2half(Wcp2[k * 64 + c]);
  } else if (idx < 25600){
    int t = idx - 24576;
    int j = t & 7, lane = (t >> 3) & 63, ks = t >> 9;
    int k = ks * 32 + (lane >> 4) * 8 + j;
    int col = lane & 15;
    Ppk2[t] = (col < 8) ? __float2half(Psd2[k * 8 + col]) : __float2half(0.f);
  } else if (idx < 26624){
    int t = idx - 25600;
    int j = t & 7, lane = (t >> 3) & 63, ks = t >> 9;
    int k = ks * 32 + (lane >> 4) * 8 + j;
    int col = lane & 15;
    Ppk3[t] = (col < 8) ? __float2half(Psd3[k * 8 + col]) : __float2half(0.f);
  }
}

// ---------------- layer-1 logits from raw x ----------------
__global__ __launch_bounds__(256)
void logits_from_x(const float* __restrict__ x, const float* __restrict__ Psd,
                   float* __restrict__ s_log, float* __restrict__ d_log, int N)
{
  int idx = blockIdx.x * 256 + threadIdx.x;
  int node = idx >> 3, q = idx & 7;
  if (node >= N) return;
  const float* xr = x + (size_t)node * 32;
  float v = 0.f;
  #pragma unroll 8
  for (int k = 0; k < 32; k++) v += xr[k] * Psd[k * 8 + q];
  if (q < 4) s_log[node * 4 + q]       = v;
  else       d_log[node * 4 + (q - 4)] = v;
}

// ---------------- aggregation: z[n,hd,k] = sum_e alpha_e^hd * x[src_e,k] ----------------
// One WAVE per destination node. Wave is split into two 32-lane edge-subgroups
// (es = lane>>5) that process edges e0 and e0+1 simultaneously.
// F=64: x fp16 [N,64]; lane owns channels {2*c2, 2*c2+1} via one half2 load.
// F=32: x f32 [N,32]; lane owns channel c2.
// Out-of-range edge slots hold alpha=0 in LDS, so no tail guards needed.
template<int F>
__global__ __launch_bounds__(256)
void gat_aggregate_z(const void* __restrict__ xin, const float* __restrict__ s_log,
                     const float* __restrict__ d_log, const int* __restrict__ off,
                     const unsigned short* __restrict__ csr, __half* __restrict__ z, int N)
{
  __shared__ float4 qa[4][64];
  __shared__ int    qs[4][64];
  const int wv   = threadIdx.x >> 6;
  const int lane = threadIdx.x & 63;
  const int n = blockIdx.x * 4 + wv;
  if (n >= N) return;
  const int beg = off[n];
  const int deg = off[n + 1] - beg;

  const float4 d4v = reinterpret_cast<const float4*>(d_log)[n];
  const float d4[4] = {d4v.x, d4v.y, d4v.z, d4v.w};

  float m[4], den[4], ex[4];
  int s = 0;

  // ---- chunk 0 softmax stats ----
  {
    const bool act = lane < deg;
    float v[4];
    if (act){
      s = csr[beg + lane];
      float4 sl = reinterpret_cast<const float4*>(s_log)[s];
      float t[4] = {sl.x, sl.y, sl.z, sl.w};
      #pragma unroll
      for (int i = 0; i < 4; i++){ float u = t[i] + d4[i]; v[i] = (u >= 0.f) ? u : NEG * u; }
    } else {
      #pragma unroll
      for (int i = 0; i < 4; i++) v[i] = -INFINITY;
    }
    #pragma unroll
    for (int i = 0; i < 4; i++){
      m[i] = wred_max64(v[i]);
      ex[i] = act ? __expf(v[i] - m[i]) : 0.f;
      den[i] = wred_sum64(ex[i]);
    }
  }
  // ---- remaining chunks (rare: deg > 64), online rescale ----
  for (int base = 64; base < deg; base += 64){
    const int k = base + lane;
    const bool act = k < deg;
    float v[4];
    if (act){
      int s2 = csr[beg + k];
      float4 sl = reinterpret_cast<const float4*>(s_log)[s2];
      float t[4] = {sl.x, sl.y, sl.z, sl.w};
      #pragma unroll
      for (int i = 0; i < 4; i++){ float u = t[i] + d4[i]; v[i] = (u >= 0.f) ? u : NEG * u; }
    } else {
      #pragma unroll
      for (int i = 0; i < 4; i++) v[i] = -INFINITY;
    }
    #pragma unroll
    for (int i = 0; i < 4; i++){
      float cm = wred_max64(v[i]);
      float mn = fmaxf(m[i], cm);
      float e2 = act ? __expf(v[i] - mn) : 0.f;
      den[i] = den[i] * __expf(m[i] - mn) + wred_sum64(e2);
      m[i] = mn;
    }
  }

  float dninv[4];
  #pragma unroll
  for (int i = 0; i < 4; i++) dninv[i] = 1.f / fmaxf(den[i], 1e-16f);

  const int es = lane >> 5;     // edge subgroup (0/1)
  const int c2 = lane & 31;     // channel (pair) index

  float a0[4] = {0.f,0.f,0.f,0.f};   // per-head acc, channel 2*c2 (or c2 for F=32)
  float a1[4] = {0.f,0.f,0.f,0.f};   // per-head acc, channel 2*c2+1 (F=64 only)

  auto accum = [&](int cnt){
    if (F == 64){
      const __half* xh = (const __half*)xin;
      #pragma unroll 2
      for (int e0 = 0; e0 < cnt; e0 += 2){
        const int e = e0 + es;
        float4 al = qa[wv][e];
        int src   = qs[wv][e];
        float2 f = __half22float2(*reinterpret_cast<const __half2*>(xh + src * 64 + 2 * c2));
        a0[0] += al.x * f.x; a1[0] += al.x * f.y;
        a0[1] += al.y * f.x; a1[1] += al.y * f.y;
        a0[2] += al.z * f.x; a1[2] += al.z * f.y;
        a0[3] += al.w * f.x; a1[3] += al.w * f.y;
      }
    } else {
      const float* xf = (const float*)xin;
      #pragma unroll 2
      for (int e0 = 0; e0 < cnt; e0 += 2){
        const int e = e0 + es;
        float4 al = qa[wv][e];
        int src   = qs[wv][e];
        float xv  = xf[src * 32 + c2];
        a0[0] += al.x * xv;
        a0[1] += al.y * xv;
        a0[2] += al.z * xv;
        a0[3] += al.w * xv;
      }
    }
  };

  if (deg <= 64){
    // fast path: chunk-0 ex already uses the final max; inactive lanes carry ex=0
    qa[wv][lane] = make_float4(ex[0] * dninv[0], ex[1] * dninv[1],
                               ex[2] * dninv[2], ex[3] * dninv[3]);
    qs[wv][lane] = s;
    WAVE_SYNC();
    accum(deg);
  } else {
    for (int base = 0; base < deg; base += 64){
      const int k = base + lane;
      int s2 = 0; float al[4] = {0.f, 0.f, 0.f, 0.f};
      if (k < deg){
        s2 = csr[beg + k];
        float4 sl = reinterpret_cast<const float4*>(s_log)[s2];
        float t[4] = {sl.x, sl.y, sl.z, sl.w};
        #pragma unroll
        for (int i = 0; i < 4; i++){
          float u = t[i] + d4[i]; u = (u >= 0.f) ? u : NEG * u;
          al[i] = __expf(u - m[i]) * dninv[i];
        }
      }
      qa[wv][lane] = make_float4(al[0], al[1], al[2], al[3]);
      qs[wv][lane] = s2;
      WAVE_SYNC();
      accum(min(64, deg - base));
      WAVE_SYNC();
    }
  }

  // combine the two edge-subgroups
  #pragma unroll
  for (int h = 0; h < 4; h++){
    a0[h] += __shfl_xor(a0[h], 32);
    if (F == 64) a1[h] += __shfl_xor(a1[h], 32);
  }

  if (lane < 32){
    if (F == 64){
      const size_t zb = (size_t)n * 256;
      #pragma unroll
      for (int h = 0; h < 4; h++){
        __half2 hv = __floats2half2_rn(a0[h], a1[h]);
        *reinterpret_cast<unsigned*>(z + zb + h * 64 + 2 * c2) =
            *reinterpret_cast<const unsigned*>(&hv);
      }
    } else {
      const size_t zb = (size_t)n * 128;
      #pragma unroll
      for (int h = 0; h < 4; h++)
        z[zb + h * 32 + c2] = __float2half(a0[h]);
    }
  }
}

// ---------------- z transform via MFMA ----------------
// x_out[n,c] = relu(z[n,:] @ Wcp + cb)  (fp16 out), plus next-layer logits via MFMA vs packed Psd.
// Wave = 16 nodes. A-frag: row=lane&15, k=(lane>>4)*8+j (contiguous 16B from z row).
// C/D: col=lane&15, row=(lane>>4)*4+reg  [m89/m91-verified layout].
template<int ZW>
__global__ __launch_bounds__(256)
void z_transform_mfma(const __half* __restrict__ z, const __half* __restrict__ Wpk,
                      const float* __restrict__ cb, const __half* __restrict__ Ppk,
                      __half* __restrict__ xo, float* __restrict__ s_log,
                      float* __restrict__ d_log, int N)
{
  __shared__ float outs[4][16][68];   // +4 pad -> 2-way banks on strided reads
  __shared__ float cbs[64];
  const int tid = threadIdx.x;
  const int wv = tid >> 6, lane = tid & 63;
  const int row = lane & 15, kg = lane >> 4;
  const int n0 = blockIdx.x * 64 + wv * 16;
  if (tid < 64) cbs[tid] = cb[tid];
  __syncthreads();

  f32x4 acc0 = {0.f,0.f,0.f,0.f}, acc1 = {0.f,0.f,0.f,0.f};
  f32x4 acc2 = {0.f,0.f,0.f,0.f}, acc3 = {0.f,0.f,0.f,0.f};
  const __half* za = z + (size_t)(n0 + row) * ZW + kg * 8;
  const f16x8* wp = reinterpret_cast<const f16x8*>(Wpk) + lane;
  #pragma unroll
  for (int ks = 0; ks < ZW / 32; ks++){
    f16x8 af = *reinterpret_cast<const f16x8*>(za + ks * 32);
    acc0 = __builtin_amdgcn_mfma_f32_16x16x32_f16(af, wp[(ks*4+0)*64], acc0, 0,0,0);
    acc1 = __builtin_amdgcn_mfma_f32_16x16x32_f16(af, wp[(ks*4+1)*64], acc1, 0,0,0);
    acc2 = __builtin_amdgcn_mfma_f32_16x16x32_f16(af, wp[(ks*4+2)*64], acc2, 0,0,0);
    acc3 = __builtin_amdgcn_mfma_f32_16x16x32_f16(af, wp[(ks*4+3)*64], acc3, 0,0,0);
  }
  #pragma unroll
  for (int r = 0; r < 4; r++){
    int rr = kg * 4 + r;
    outs[wv][rr][ 0 + row] = fmaxf(acc0[r] + cbs[ 0 + row], 0.f);
    outs[wv][rr][16 + row] = fmaxf(acc1[r] + cbs[16 + row], 0.f);
    outs[wv][rr][32 + row] = fmaxf(acc2[r] + cbs[32 + row], 0.f);
    outs[wv][rr][48 + row] = fmaxf(acc3[r] + cbs[48 + row], 0.f);
  }
  WAVE_SYNC();

  // xo (fp16) coalesced-ish write: 4 x uint2 (4 halves) per lane
  #pragma unroll
  for (int i = 0; i < 4; i++){
    int idx = lane + 64 * i;
    int nn = idx >> 4, part = idx & 15;
    int node = n0 + nn;
    if (node < N){
      const float* o = &outs[wv][nn][part * 4];
      __half2 h0 = __floats2half2_rn(o[0], o[1]);
      __half2 h1 = __floats2half2_rn(o[2], o[3]);
      uint2 u;
      u.x = *reinterpret_cast<const unsigned*>(&h0);
      u.y = *reinterpret_cast<const unsigned*>(&h1);
      *reinterpret_cast<uint2*>(xo + (size_t)node * 64 + part * 4) = u;
    }
  }

  // next-layer logits: [16 x 64] @ Ppk (cols 0-7 = s/d heads)
  f32x4 lacc = {0.f,0.f,0.f,0.f};
  const f16x8* pp = reinterpret_cast<const f16x8*>(Ppk) + lane;
  #pragma unroll
  for (int ks = 0; ks < 2; ks++){
    f16x8 af;
    #pragma unroll
    for (int j = 0; j < 8; j++) af[j] = (_Float16)outs[wv][row][ks * 32 + kg * 8 + j];
    lacc = __builtin_amdgcn_mfma_f32_16x16x32_f16(af, pp[ks * 64], lacc, 0,0,0);
  }
  if (row < 8){
    float* dst = (row < 4) ? s_log : d_log;
    int q = row & 3;
    #pragma unroll
    for (int r = 0; r < 4; r++){
      int node = n0 + kg * 4 + r;
      if (node < N) dst[node * 4 + q] = lacc[r];
    }
  }
}

// ---------------- pooling + fused layer-3 projection + MLP1 ----------------
__global__ __launch_bounds__(256)
void graph_bounds(const int* __restrict__ batch, int N, int G, int* __restrict__ bnd){
  int g = blockIdx.x * 256 + threadIdx.x;
  if (g > G) return;
  if (g == G){ bnd[G] = N; return; }
  int lo = 0, hi = N;
  while (lo < hi){ int mid = (lo + hi) >> 1; if (batch[mid] < g) lo = mid + 1; else hi = mid; }
  bnd[g] = lo;
}

// mean(z3)@Wcp3 + cb3 -> t[64]; g1 = relu(t@m1w + m1b)   (layer-3 head linear has no relu,
// and mean-pool is linear, so projecting the pooled z is exact)
__global__ __launch_bounds__(256)
void pool_mlp1(const __half* __restrict__ z3, const int* __restrict__ bnd,
               const float* __restrict__ Wcp3, const float* __restrict__ cb3,
               const float* __restrict__ m1w, const float* __restrict__ m1b,
               float* __restrict__ g1)
{
  const int g = blockIdx.x, tid = threadIdx.x;
  const int s = bnd[g], e = bnd[g + 1];
  float s0 = 0.f, s1 = 0.f;
  int n = s;
  for (; n + 1 < e; n += 2){
    s0 += __half2float(z3[(size_t)n * 256 + tid]);
    s1 += __half2float(z3[(size_t)(n + 1) * 256 + tid]);
  }
  if (n < e) s0 += __half2float(z3[(size_t)n * 256 + tid]);
  __shared__ float zbar[256];
  zbar[tid] = (s0 + s1) / (float)max(e - s, 1);
  __syncthreads();
  const int c = tid & 63, part = tid >> 6;
  float tp = 0.f;
  #pragma unroll 8
  for (int k = part * 64; k < part * 64 + 64; k++) tp += zbar[k] * Wcp3[k * 64 + c];
  __shared__ float tsh[4][64];
  tsh[part][c] = tp;
  __syncthreads();
  __shared__ float tvec[64];
  if (tid < 64)
    tvec[tid] = tsh[0][tid] + tsh[1][tid] + tsh[2][tid] + tsh[3][tid] + cb3[tid];
  __syncthreads();
  float a = m1b[tid];
  #pragma unroll 8
  for (int cc = 0; cc < 64; cc++) a += tvec[cc] * m1w[cc * 256 + tid];
  g1[g * 256 + tid] = fmaxf(a, 0.f);
}

__global__ __launch_bounds__(256)
void mlp2_kernel(const float* __restrict__ g1, const float* __restrict__ w,
                 const float* __restrict__ b, float* __restrict__ out)
{
  int g = blockIdx.x;
  int tid = threadIdx.x;
  __shared__ float row[256];
  row[tid] = g1[g * 256 + tid];
  __syncthreads();
  float acc = b[tid];
  for (int k = 0; k < 256; k++) acc += row[k] * w[k * 256 + tid];
  out[g * 256 + tid] = acc;
}

// ---------------- launcher ----------------
extern "C" void kernel_launch(void* const* d_in, const int* in_sizes, int n_in,
                              void* d_out, int out_size, void* d_ws, size_t ws_size,
                              hipStream_t stream)
{
  const float* x     = (const float*)d_in[0];
  const int*   ei    = (const int*)d_in[1];
  const int*   batch = (const int*)d_in[2];
  const float* W1  = (const float*)d_in[4];
  const float* a1s = (const float*)d_in[5];
  const float* a1d = (const float*)d_in[6];
  const float* b1  = (const float*)d_in[7];
  const float* h1w = (const float*)d_in[8];
  const float* h1b = (const float*)d_in[9];
  const float* W2  = (const float*)d_in[10];
  const float* a2s = (const float*)d_in[11];
  const float* a2d = (const float*)d_in[12];
  const float* b2  = (const float*)d_in[13];
  const float* h2w = (const float*)d_in[14];
  const float* h2b = (const float*)d_in[15];
  const float* W3  = (const float*)d_in[16];
  const float* a3s = (const float*)d_in[17];
  const float* a3d = (const float*)d_in[18];
  const float* b3  = (const float*)d_in[19];
  const float* h3w = (const float*)d_in[20];
  const float* h3b = (const float*)d_in[21];
  const float* m1w = (const float*)d_in[22];
  const float* m1b = (const float*)d_in[23];
  const float* m2w = (const float*)d_in[24];
  const float* m2b = (const float*)d_in[25];

  const int N = in_sizes[0] / 32;
  const int E = in_sizes[1] / 2;
  const int G = out_size / 256;
  const int Etot = E + N;
  const int nb = (N + 255) / 256;

  char* p = (char*)d_ws;
  auto alloc = [&](size_t bytes) -> void* {
    void* r = (void*)p;
    p += ((bytes + 255) / 256) * 256;
    return r;
  };
  __half* zbuf   = (__half*)alloc((size_t)N * GHC * 2);
  __half* xh1    = (__half*)alloc((size_t)N * CH * 2);
  __half* xh2    = (__half*)alloc((size_t)N * CH * 2);
  float* s_log   = (float*)alloc((size_t)N * HD * 4);
  float* d_log   = (float*)alloc((size_t)N * HD * 4);
  int*   counts  = (int*)alloc((size_t)N * 4);
  int*   offs    = (int*)alloc((size_t)(N + 1) * 4);
  int*   fill    = (int*)alloc((size_t)N * 4);
  unsigned short* csr = (unsigned short*)alloc((size_t)Etot * 2);
  int*   blkS    = (int*)alloc((size_t)nb * 4);
  int*   carry   = (int*)alloc((size_t)nb * 4);
  int*   bnd     = (int*)alloc((size_t)(G + 1) * 4);
  float* g1buf   = (float*)alloc((size_t)G * 256 * 4);
  float* Wcp1    = (float*)alloc(128 * 64 * 4);
  float* Wcp2    = (float*)alloc(256 * 64 * 4);
  float* Wcp3    = (float*)alloc(256 * 64 * 4);
  float* Psd1    = (float*)alloc(32 * 8 * 4);
  float* Psd2    = (float*)alloc(64 * 8 * 4);
  float* Psd3    = (float*)alloc(64 * 8 * 4);
  float* cb1     = (float*)alloc(64 * 4);
  float* cb2     = (float*)alloc(64 * 4);
  float* cb3     = (float*)alloc(64 * 4);
  __half* Wpk1   = (__half*)alloc(128 * 64 * 2);
  __half* Wpk2   = (__half*)alloc(256 * 64 * 2);
  __half* Ppk2   = (__half*)alloc(1024 * 2);
  __half* Ppk3   = (__half*)alloc(1024 * 2);

  hipMemsetAsync(counts, 0, (size_t)N * 4, stream);
  hipMemsetAsync(fill,   0, (size_t)N * 4, stream);

  count_deg<<<(Etot + 255) / 256, 256, 0, stream>>>(ei, E, N, counts);
  scan_local<<<nb, 256, 0, stream>>>(counts, N, offs, blkS);
  scan_carry<<<1, 256, 0, stream>>>(blkS, nb, carry);
  scan_add<<<nb, 256, 0, stream>>>(offs, carry, N, Etot);
  fill_csr<<<(Etot + 255) / 256, 256, 0, stream>>>(ei, E, N, offs, fill, csr);
  graph_bounds<<<(G + 256) / 256, 256, 0, stream>>>(batch, N, G, bnd);

  fuse_weights<<<33, 256, 0, stream>>>(W1, a1s, a1d, b1, h1w, h1b, 32, Wcp1, Psd1, cb1);
  fuse_weights<<<65, 256, 0, stream>>>(W2, a2s, a2d, b2, h2w, h2b, 64, Wcp2, Psd2, cb2);
  fuse_weights<<<65, 256, 0, stream>>>(W3, a3s, a3d, b3, h3w, h3b, 64, Wcp3, Psd3, cb3);
  pack_all<<<104, 256, 0, stream>>>(Wcp1, Wcp2, Psd2, Psd3, Wpk1, Wpk2, Ppk2, Ppk3);

  const int ab = (N + 3) / 4;
  const int zb = (N + 63) / 64;

  logits_from_x<<<((size_t)N * 8 + 255) / 256, 256, 0, stream>>>(x, Psd1, s_log, d_log, N);

  gat_aggregate_z<32><<<ab, 256, 0, stream>>>(x, s_log, d_log, offs, csr, zbuf, N);
  z_transform_mfma<128><<<zb, 256, 0, stream>>>(zbuf, Wpk1, cb1, Ppk2, xh1, s_log, d_log, N);

  gat_aggregate_z<64><<<ab, 256, 0, stream>>>(xh1, s_log, d_log, offs, csr, zbuf, N);
  z_transform_mfma<256><<<zb, 256, 0, stream>>>(zbuf, Wpk2, cb2, Ppk3, xh2, s_log, d_log, N);

  gat_aggregate_z<64><<<ab, 256, 0, stream>>>(xh2, s_log, d_log, offs, csr, zbuf, N);

  pool_mlp1<<<G, 256, 0, stream>>>(zbuf, bnd, Wcp3, cb3, m1w, m1b, g1buf);
  mlp2_kernel<<<G, 256, 0, stream>>>(g1buf, m2w, m2b, (float*)d_out);
}